// Round 2
// baseline (478.908 us; speedup 1.0000x reference)
//
#include <hip/hip_runtime.h>
#include <hip/hip_bf16.h>
#include <stdint.h>

typedef unsigned short u16;
typedef __attribute__((ext_vector_type(8))) short bf16x8;
typedef __attribute__((ext_vector_type(4))) float floatx4;

__device__ __forceinline__ float bf2f(u16 v){ return __uint_as_float(((unsigned)v)<<16); }
__device__ __forceinline__ u16 f2bf(float f){
  unsigned u = __float_as_uint(f);
  unsigned r = 0x7fffu + ((u>>16)&1u);
  return (u16)((u+r)>>16);
}
__device__ __forceinline__ float lrelu(float x){ return x > 0.f ? x : 0.2f*x; }
__device__ __forceinline__ float sigm(float t){
  t = fminf(fmaxf(t, -30.f), 30.f);
  return 1.f/(1.f + expf(-t));
}

#define GLOAD16(ldsdst, gsrc) \
  __builtin_amdgcn_global_load_lds((const __attribute__((address_space(1))) void*)(gsrc), \
      (__attribute__((address_space(3))) void*)(ldsdst), 16, 0, 0)

// ---------------------------------------------------------------------------
// dtype detector: flags[0]=1 -> float inputs are f32 (else bf16)
//                 flags[1]=1 -> node_type is int64 (else int32)
// f32 read as bf16 pairs: even u16 = mantissa garbage, ~80% wild exponents.
// genuine bf16 N(0,1): exponents cluster near 127, ~0 wild.
// ---------------------------------------------------------------------------
__global__ void k_detect(const u16* __restrict__ nodes_raw,
                         const int* __restrict__ ntype_raw, int* flags)
{
  __shared__ int s_wild, s_nz;
  if (threadIdx.x == 0){ s_wild = 0; s_nz = 0; }
  __syncthreads();
  int wild = 0;
#pragma unroll
  for (int i = 0; i < 16; i++){
    u16 w = nodes_raw[threadIdx.x*16 + i];
    int e = (w >> 7) & 0xFF;
    if (e != 0 && (e < 102 || e > 152)) wild++;
  }
  int nz = 0;
  if (threadIdx.x < 255 && ntype_raw[2*threadIdx.x + 1] != 0) nz = 1;
  atomicAdd(&s_wild, wild);
  atomicAdd(&s_nz, nz);
  __syncthreads();
  if (threadIdx.x == 0){
    flags[0] = (s_wild > 1024) ? 1 : 0;
    flags[1] = (s_nz == 0) ? 1 : 0;
  }
}

// canonicalize one float input to bf16 (4 elements/thread)
__global__ __launch_bounds__(256)
void k_canon(const void* __restrict__ src, u16* __restrict__ dst, int n,
             const int* __restrict__ flags)
{
  int i = blockIdx.x*256 + threadIdx.x;
  if (i*4 >= n) return;
  if (flags[0]) {
    float4 v = ((const float4*)src)[i];
    ushort4 o;
    o.x = f2bf(v.x); o.y = f2bf(v.y); o.z = f2bf(v.z); o.w = f2bf(v.w);
    ((ushort4*)dst)[i] = o;
  } else {
    ((uint2*)dst)[i] = ((const uint2*)src)[i];
  }
}

// ---------------------------------------------------------------------------
// Generic 128x128 bf16 GEMM, C = A(MxK) * B^T (B stored [N][K] K-major),
// fp32 accumulate, templated epilogue. BK=32, m97 structure.
// ---------------------------------------------------------------------------
template<class Epi>
__global__ __launch_bounds__(256)
void gemm_bt(const u16* __restrict__ A, int ldA, long sAz,
             const u16* __restrict__ B, int ldB, long sBz,
             int K, Epi epi)
{
  __shared__ __align__(16) u16 As[128][32];
  __shared__ __align__(16) u16 Bs[128][32];
  const int bn = blockIdx.x, bm = blockIdx.y, bz = blockIdx.z;
  const int tid  = threadIdx.x;
  const int lane = tid & 63;
  const int wave = tid >> 6;
  const int wm = (wave & 1) << 6;
  const int wn = (wave >> 1) << 6;
  const int mrow = lane & 15;
  const int quad = lane >> 4;

  const u16* Ab = A + (long)bz*sAz + (long)bm*128*ldA;
  const u16* Bb = B + (long)bz*sBz + (long)bn*128*ldB;
  const int srow = tid >> 2;          // 0..63
  const int scol = (tid & 3) << 3;    // 8 bf16 = 16B per lane
  const u16* gA0 = Ab + (long)srow*ldA + scol;
  const u16* gA1 = Ab + (long)(srow+64)*ldA + scol;
  const u16* gB0 = Bb + (long)srow*ldB + scol;
  const u16* gB1 = Bb + (long)(srow+64)*ldB + scol;
  u16* lA0 = &As[srow][scol];          // byte offset = tid*16 (lane-contiguous)
  u16* lA1 = &As[srow+64][scol];
  u16* lB0 = &Bs[srow][scol];
  u16* lB1 = &Bs[srow+64][scol];

  floatx4 acc[4][4];
#pragma unroll
  for (int i=0;i<4;i++)
#pragma unroll
    for (int j=0;j<4;j++) acc[i][j] = 0.f;

  for (int k0 = 0; k0 < K; k0 += 32) {
    GLOAD16(lA0, gA0); GLOAD16(lA1, gA1);
    GLOAD16(lB0, gB0); GLOAD16(lB1, gB1);
    gA0 += 32; gA1 += 32; gB0 += 32; gB1 += 32;
    asm volatile("s_waitcnt vmcnt(0)" ::: "memory");
    __syncthreads();
    bf16x8 af[4], bfr[4];
#pragma unroll
    for (int i=0;i<4;i++) af[i]  = *(const bf16x8*)&As[wm + i*16 + mrow][quad*8];
#pragma unroll
    for (int i=0;i<4;i++) bfr[i] = *(const bf16x8*)&Bs[wn + i*16 + mrow][quad*8];
#pragma unroll
    for (int mi=0;mi<4;mi++)
#pragma unroll
      for (int ni=0;ni<4;ni++)
        acc[mi][ni] = __builtin_amdgcn_mfma_f32_16x16x32_bf16(af[mi], bfr[ni], acc[mi][ni], 0,0,0);
    __syncthreads();
  }

  // C/D layout: col = lane&15, row = quad*4 + reg  [measured m89/m91]
#pragma unroll
  for (int mi=0;mi<4;mi++)
#pragma unroll
    for (int ni=0;ni<4;ni++) {
      const int col  = (bn<<7) + wn + ni*16 + mrow;
      const int row0 = (bm<<7) + wm + mi*16 + quad*4;
#pragma unroll
      for (int r=0;r<4;r++)
        epi(row0 + r, col, bz, acc[mi][ni][r]);
    }
}

// --- epilogues --------------------------------------------------------------
struct EpiTyped {   // bz = edge type t; write only rows with node_type==t+2
  const int* ntype; const int* flags; u16* node_in; u16* node_out;
  __device__ void operator()(int row, int col, int bz, float v) const {
    int t = flags[1] ? ntype[2*row] : ntype[row];   // int64: low word (LE)
    if (t == bz + 2) {
      u16 h = f2bf(v);
      if (col < 512) node_in[(long)row*512 + col] = h;
      else           node_out[(long)row*512 + (col-512)] = h;
    }
  }
};
struct EpiPV {      // bz = batch; scale row by inv_l, write into X at colOff
  const float* inv_l; u16* X; int colOff;
  __device__ void operator()(int row, int col, int bz, float v) const {
    long gr = (long)bz*1024 + row;
    X[gr*1536 + colOff + col] = f2bf(v * inv_l[gr]);
  }
};
struct EpiG1 {      // cols [0,512): r-gate -> rn; [512,1024): z; [1024,1536): tpart
  const u16* nodes; const u16* b_r; const u16* b_z;
  u16* rn; u16* zbuf; float* tpart;
  __device__ void operator()(int row, int col, int bz, float v) const {
    if (col < 512) {
      float r = sigm(v + bf2f(b_r[col]));
      float nv = bf2f(nodes[(long)row*512 + col]);
      rn[(long)row*512 + col] = f2bf(r * nv);
    } else if (col < 1024) {
      int c = col - 512;
      zbuf[(long)row*512 + c] = f2bf(sigm(v + bf2f(b_z[c])));
    } else {
      tpart[(long)row*512 + (col-1024)] = v;
    }
  }
};
struct EpiG2 {      // final: h_hat = tanh(tpart + v + b_t); out = (1-z)n + z h_hat
  const float* tpart; const u16* zbuf; const u16* nodes; const u16* b_t;
  const int* flags; void* out;
  __device__ void operator()(int row, int col, int bz, float v) const {
    long idx = (long)row*512 + col;
    float t = v + tpart[idx] + bf2f(b_t[col]);
    t = fminf(fmaxf(t, -15.f), 15.f);
    float h = tanhf(t);
    float z = bf2f(zbuf[idx]);
    float nv = bf2f(nodes[idx]);
    float o = (1.f - z)*nv + z*h;
    if (flags[0]) ((float*)out)[idx] = o;
    else          ((u16*)out)[idx]   = f2bf(o);
  }
};

// --- tiled bf16 transpose: dst[c*ldD + r] = src[r*ldS + c] -----------------
__global__ __launch_bounds__(256)
void k_transpose(u16* __restrict__ dst, int ldD, long dzs,
                 const u16* __restrict__ src, int ldS, long szs)
{
  __shared__ u16 tile[32][33];
  src += (long)blockIdx.z * szs;
  dst += (long)blockIdx.z * dzs;
  const int c0 = blockIdx.x*32, r0 = blockIdx.y*32;
  const int tx = threadIdx.x, ty = threadIdx.y;
#pragma unroll
  for (int i=0;i<32;i+=8)
    tile[ty+i][tx] = src[(long)(r0+ty+i)*ldS + c0 + tx];
  __syncthreads();
#pragma unroll
  for (int i=0;i<32;i+=8)
    dst[(long)(c0+ty+i)*ldD + r0 + tx] = tile[tx][ty+i];
}

// --- copy nodes into X[:,1024:1536] ----------------------------------------
__global__ __launch_bounds__(256)
void k_copyX(const u16* __restrict__ nodes, u16* __restrict__ X)
{
  long idx = (long)blockIdx.x*256 + threadIdx.x;   // one uint4 (8 bf16) each
  long r = idx >> 6;
  int  c = (int)(idx & 63) << 3;
  *(uint4*)&X[r*1536 + 1024 + c] = *(const uint4*)&nodes[r*512 + c];
}

__device__ __forceinline__ void load8f(float* f, const u16* p){
  uint4 q = *(const uint4*)p;
  unsigned w[4] = {q.x, q.y, q.z, q.w};
#pragma unroll
  for (int i=0;i<4;i++){ f[2*i] = bf2f((u16)(w[i]&0xffffu)); f[2*i+1] = bf2f((u16)(w[i]>>16)); }
}

// --- per-row scalar projections: 4 dots of length 512 per node -------------
__global__ __launch_bounds__(256)
void k_svec(const u16* __restrict__ nodes, const u16* __restrict__ nin, const u16* __restrict__ nout,
            const u16* __restrict__ aiq, const u16* __restrict__ aiv,
            const u16* __restrict__ aoq, const u16* __restrict__ aov,
            float* sq_in, float* sq_out, float* sv_in, float* sv_out)
{
  const int lane = threadIdx.x & 63, wave = threadIdx.x >> 6;
  const long row = (long)blockIdx.x*4 + wave;
  const int c = lane << 3;
  float xn[8], xi[8], xo[8], q1[8], v1[8], q2[8], v2[8];
  load8f(xn, nodes + row*512 + c);
  load8f(xi, nin   + row*512 + c);
  load8f(xo, nout  + row*512 + c);
  load8f(q1, aiq + c); load8f(v1, aiv + c);
  load8f(q2, aoq + c); load8f(v2, aov + c);
  float s0=0,s1=0,s2=0,s3=0;
#pragma unroll
  for (int j=0;j<8;j++){ s0 += xn[j]*q1[j]; s1 += xn[j]*q2[j]; s2 += xi[j]*v1[j]; s3 += xo[j]*v2[j]; }
#pragma unroll
  for (int off=32; off; off>>=1){
    s0 += __shfl_xor(s0, off);
    s1 += __shfl_xor(s1, off);
    s2 += __shfl_xor(s2, off);
    s3 += __shfl_xor(s3, off);
  }
  if (lane==0){ sq_in[row]=s0; sq_out[row]=s1; sv_in[row]=s2; sv_out[row]=s3; }
}

// --- masked-softmax stats + materialize P (bf16), one wave per row ---------
__global__ __launch_bounds__(256)
void k_stats(const int* __restrict__ mask, const float* __restrict__ sq,
             const float* __restrict__ sv, u16* __restrict__ P, float* __restrict__ inv_l)
{
  const int lane = threadIdx.x & 63, wave = threadIdx.x >> 6;
  const long row = (long)blockIdx.x*4 + wave;            // b*1024 + i
  const long b = row >> 10;
  const int* mrow = mask + row*1024;
  const float* svb = sv + b*1024;
  const float qs = sq[row];
  float m = -3.0e38f;
#pragma unroll
  for (int it=0; it<8; ++it) {
    int j = it*128 + lane*2;
    int2 mk = *(const int2*)&mrow[j];
    float2 s = *(const float2*)&svb[j];
    float e0 = mk.x > 0 ? lrelu(qs + s.x) : -1e9f;
    float e1 = mk.y > 0 ? lrelu(qs + s.y) : -1e9f;
    m = fmaxf(m, fmaxf(e0, e1));
  }
#pragma unroll
  for (int off=32; off; off>>=1) m = fmaxf(m, __shfl_xor(m, off));
  float l = 0.f;
#pragma unroll
  for (int it=0; it<8; ++it) {
    int j = it*128 + lane*2;
    int2 mk = *(const int2*)&mrow[j];
    float2 s = *(const float2*)&svb[j];
    float e0 = mk.x > 0 ? lrelu(qs + s.x) : -1e9f;
    float e1 = mk.y > 0 ? lrelu(qs + s.y) : -1e9f;
    float p0 = expf(e0 - m), p1 = expf(e1 - m);
    *(unsigned*)&P[row*1024 + j] = (unsigned)f2bf(p0) | ((unsigned)f2bf(p1) << 16);
    l += p0 + p1;
  }
#pragma unroll
  for (int off=32; off; off>>=1) l += __shfl_xor(l, off);
  if (lane==0) inv_l[row] = 1.f / l;
}

// ---------------------------------------------------------------------------
extern "C" void kernel_launch(void* const* d_in, const int* in_sizes, int n_in,
                              void* d_out, int out_size, void* d_ws, size_t ws_size,
                              hipStream_t stream)
{
  const void* nodes_r   = d_in[0];
  const int*  mask      = (const int*)d_in[1];
  const int*  ntype     = (const int*)d_in[2];
  const void* W_in_r    = d_in[3];
  const void* W_out_r   = d_in[4];
  const void* a_in_q_r  = d_in[5];
  const void* a_in_v_r  = d_in[6];
  const void* a_out_q_r = d_in[7];
  const void* a_out_v_r = d_in[8];
  const void* W_r_r     = d_in[9];
  const void* b_r_r     = d_in[10];
  const void* W_z_r     = d_in[11];
  const void* b_z_r     = d_in[12];
  const void* W_t_r     = d_in[13];
  const void* b_t_r     = d_in[14];

  char* base = (char*)d_ws;
  size_t o = 0;
  auto alloc = [&](size_t bytes){ void* p = base + o; o += (bytes + 255) & ~size_t(255); return p; };
  int*  flags   = (int*)alloc(256);
  u16* cn_nodes = (u16*)alloc(8192ll*512*2);
  u16* cn_Win   = (u16*)alloc(3ll*512*512*2);
  u16* cn_Wout  = (u16*)alloc(3ll*512*512*2);
  u16* cn_Wr    = (u16*)alloc(1536ll*512*2);
  u16* cn_Wz    = (u16*)alloc(1536ll*512*2);
  u16* cn_Wt    = (u16*)alloc(1536ll*512*2);
  u16* cn_aiq   = (u16*)alloc(512*2);
  u16* cn_aiv   = (u16*)alloc(512*2);
  u16* cn_aoq   = (u16*)alloc(512*2);
  u16* cn_aov   = (u16*)alloc(512*2);
  u16* cn_br    = (u16*)alloc(512*2);
  u16* cn_bz    = (u16*)alloc(512*2);
  u16* cn_bt    = (u16*)alloc(512*2);
  u16* node_in  = (u16*)alloc(8192ll*512*2);
  u16* node_out = (u16*)alloc(8192ll*512*2);   // adjacent to node_in (joint memset)
  u16* VtIn     = (u16*)alloc(8ll*512*1024*2); // tpart (f32) aliases VtIn+VtOut
  u16* VtOut    = (u16*)alloc(8ll*512*1024*2);
  u16* X        = (u16*)alloc(8192ll*1536*2);
  u16* P        = (u16*)alloc(8ll*1024*1024*2); // rn + zbuf alias P after PV GEMMs
  u16* Wio_t    = (u16*)alloc(3ll*1024*512*2);
  u16* Wbig_t   = (u16*)alloc(1536ll*1536*2);
  u16* Wt3_t    = (u16*)alloc(512ll*512*2);
  float* sq_in  = (float*)alloc(8192*4);
  float* sq_out = (float*)alloc(8192*4);
  float* sv_in  = (float*)alloc(8192*4);
  float* sv_out = (float*)alloc(8192*4);
  float* il_in  = (float*)alloc(8192*4);
  float* il_out = (float*)alloc(8192*4);
  float* tpart  = (float*)VtIn;      // 16 MB, alias (dead after PV GEMMs)
  u16*   rn     = P;                  // 8 MB
  u16*   zbuf   = P + 8192ll*512;     // 8 MB

  hipMemsetAsync(node_in, 0, 2ll*8192*512*2, stream);     // node_in + node_out
  hipMemsetAsync(Wbig_t, 0, 1536ll*1536*2, stream);       // zero-pad for W_t top block

  // dtype detection + canonicalization to bf16
  k_detect<<<1, 256, 0, stream>>>((const u16*)nodes_r, ntype, flags);
  auto canon = [&](const void* src, u16* dst, int n){
    k_canon<<<(n/4 + 255)/256, 256, 0, stream>>>(src, dst, n, flags);
  };
  canon(nodes_r,   cn_nodes, 8192*512);
  canon(W_in_r,    cn_Win,   3*512*512);
  canon(W_out_r,   cn_Wout,  3*512*512);
  canon(W_r_r,     cn_Wr,    1536*512);
  canon(W_z_r,     cn_Wz,    1536*512);
  canon(W_t_r,     cn_Wt,    1536*512);
  canon(a_in_q_r,  cn_aiq, 512); canon(a_in_v_r,  cn_aiv, 512);
  canon(a_out_q_r, cn_aoq, 512); canon(a_out_v_r, cn_aov, 512);
  canon(b_r_r, cn_br, 512); canon(b_z_r, cn_bz, 512); canon(b_t_r, cn_bt, 512);

  dim3 tb(32,8);
  // Wio_t[t][n][k]: n<512 -> W_in[t][k][n], else W_out[t][k][n-512]
  k_transpose<<<dim3(16,16,3), tb, 0, stream>>>(Wio_t,             512, 1024ll*512, cn_Win,  512, 512ll*512);
  k_transpose<<<dim3(16,16,3), tb, 0, stream>>>(Wio_t + 512ll*512, 512, 1024ll*512, cn_Wout, 512, 512ll*512);
  // Wbig_t[n][k] (1536x1536): [W_r | W_z | W_t(:1024) (zero-padded k>=1024)]
  k_transpose<<<dim3(16,48,1), tb, 0, stream>>>(Wbig_t,               1536, 0, cn_Wr, 512, 0);
  k_transpose<<<dim3(16,48,1), tb, 0, stream>>>(Wbig_t + 512ll*1536,  1536, 0, cn_Wz, 512, 0);
  k_transpose<<<dim3(16,32,1), tb, 0, stream>>>(Wbig_t + 1024ll*1536, 1536, 0, cn_Wt, 512, 0);
  k_transpose<<<dim3(16,16,1), tb, 0, stream>>>(Wt3_t, 512, 0, cn_Wt + 1024ll*512, 512, 0);

  // typed linear: 3 GEMMs (grid.z=t), masked epilogue
  gemm_bt<<<dim3(8,64,3), 256, 0, stream>>>(cn_nodes, 512, 0ll, Wio_t, 512, 1024ll*512, 512,
                                            EpiTyped{ntype, flags, node_in, node_out});
  // V^T per batch for PV B-operand
  k_transpose<<<dim3(16,32,8), tb, 0, stream>>>(VtIn,  1024, 512ll*1024, node_in,  512, 1024ll*512);
  k_transpose<<<dim3(16,32,8), tb, 0, stream>>>(VtOut, 1024, 512ll*1024, node_out, 512, 1024ll*512);

  k_svec<<<2048, 256, 0, stream>>>(cn_nodes, node_in, node_out, cn_aiq, cn_aiv, cn_aoq, cn_aov,
                                   sq_in, sq_out, sv_in, sv_out);
  k_copyX<<<2048, 256, 0, stream>>>(cn_nodes, X);

  // GAT in: stats -> P, then PV GEMM into X[:,0:512]
  k_stats<<<2048, 256, 0, stream>>>(mask, sq_in, sv_in, P, il_in);
  gemm_bt<<<dim3(4,8,8), 256, 0, stream>>>(P, 1024, 1024ll*1024, VtIn, 1024, 512ll*1024, 1024,
                                           EpiPV{il_in, X, 0});
  // GAT out (PV-out must finish before rn/zbuf alias writes): into X[:,512:1024]
  k_stats<<<2048, 256, 0, stream>>>(mask + 8ll*1024*1024, sq_out, sv_out, P, il_out);
  gemm_bt<<<dim3(4,8,8), 256, 0, stream>>>(P, 1024, 1024ll*1024, VtOut, 1024, 512ll*1024, 1024,
                                           EpiPV{il_out, X, 512});

  // GGNN: fused r/z/tpart GEMM, then final K=512 GEMM with gate epilogue
  gemm_bt<<<dim3(12,64,1), 256, 0, stream>>>(X, 1536, 0ll, Wbig_t, 1536, 0ll, 1536,
                                             EpiG1{cn_nodes, cn_br, cn_bz, rn, zbuf, tpart});
  gemm_bt<<<dim3(4,64,1), 256, 0, stream>>>(rn, 512, 0ll, Wt3_t, 512, 0ll, 512,
                                            EpiG2{tpart, zbuf, cn_nodes, cn_bt, flags, (void*)d_out});
}

// Round 3
// 435.420 us; speedup vs baseline: 1.0999x; 1.0999x over previous
//
#include <hip/hip_runtime.h>
#include <hip/hip_bf16.h>
#include <stdint.h>

typedef unsigned short u16;
typedef __attribute__((ext_vector_type(8))) short bf16x8;
typedef __attribute__((ext_vector_type(4))) float floatx4;

__device__ __forceinline__ float bf2f(u16 v){ return __uint_as_float(((unsigned)v)<<16); }
__device__ __forceinline__ u16 f2bf(float f){
  unsigned u = __float_as_uint(f);
  unsigned r = 0x7fffu + ((u>>16)&1u);
  return (u16)((u+r)>>16);
}
__device__ __forceinline__ float lrelu(float x){ return x > 0.f ? x : 0.2f*x; }
__device__ __forceinline__ float sigm(float t){
  t = fminf(fmaxf(t, -30.f), 30.f);
  return 1.f/(1.f + expf(-t));
}

#define GLOAD16(ldsdst, gsrc) \
  __builtin_amdgcn_global_load_lds((const __attribute__((address_space(1))) void*)(gsrc), \
      (__attribute__((address_space(3))) void*)(ldsdst), 16, 0, 0)

// ---------------------------------------------------------------------------
// dtype detector: flags[0]=1 -> float inputs are f32; flags[1]=1 -> node_type int64
// ---------------------------------------------------------------------------
__global__ void k_detect(const u16* __restrict__ nodes_raw,
                         const int* __restrict__ ntype_raw, int* flags)
{
  __shared__ int s_wild, s_nz;
  if (threadIdx.x == 0){ s_wild = 0; s_nz = 0; }
  __syncthreads();
  int wild = 0;
#pragma unroll
  for (int i = 0; i < 16; i++){
    u16 w = nodes_raw[threadIdx.x*16 + i];
    int e = (w >> 7) & 0xFF;
    if (e != 0 && (e < 102 || e > 152)) wild++;
  }
  int nz = 0;
  if (threadIdx.x < 255 && ntype_raw[2*threadIdx.x + 1] != 0) nz = 1;
  atomicAdd(&s_wild, wild);
  atomicAdd(&s_nz, nz);
  __syncthreads();
  if (threadIdx.x == 0){
    flags[0] = (s_wild > 1024) ? 1 : 0;
    flags[1] = (s_nz == 0) ? 1 : 0;
  }
}

// --- merged canonicalization of all 13 float tensors -----------------------
struct CanonDesc {
  const void* src[13];
  u16*        dst[13];
  int startBlk[13];
  int n4[13];
};
__global__ __launch_bounds__(256)
void k_canon_all(CanonDesc d, const int* __restrict__ flags)
{
  int blk = blockIdx.x;
  int seg = 0;
#pragma unroll
  for (int s = 1; s < 13; s++) if (blk >= d.startBlk[s]) seg = s;
  int i = (blk - d.startBlk[seg])*256 + threadIdx.x;
  if (i >= d.n4[seg]) return;
  if (flags[0]) {
    float4 v = ((const float4*)d.src[seg])[i];
    ushort4 o2;
    o2.x = f2bf(v.x); o2.y = f2bf(v.y); o2.z = f2bf(v.z); o2.w = f2bf(v.w);
    ((ushort4*)d.dst[seg])[i] = o2;
  } else {
    ((uint2*)d.dst[seg])[i] = ((const uint2*)d.src[seg])[i];
  }
}

// --- per-type row index lists ----------------------------------------------
__global__ void k_build_idx(const int* __restrict__ ntype, const int* __restrict__ flags,
                            int* __restrict__ idx, int* __restrict__ cnt)
{
  __shared__ int c[3];
  if (threadIdx.x < 3) c[threadIdx.x] = 0;
  __syncthreads();
  const int i64 = flags[1];
  for (int i = threadIdx.x; i < 8192; i += 256){
    int t = i64 ? ntype[2*i] : ntype[i];
    if (t >= 2 && t <= 4){
      int p = atomicAdd(&c[t-2], 1);
      idx[(t-2)*8192 + p] = i;
    }
  }
  __syncthreads();
  if (threadIdx.x < 3) cnt[threadIdx.x] = c[threadIdx.x];
}

// ---------------------------------------------------------------------------
// Generic 128x128 bf16 GEMM, C = A(MxK) * B^T (B stored [N][K] K-major).
// ---------------------------------------------------------------------------
template<class Epi>
__global__ __launch_bounds__(256)
void gemm_bt(const u16* __restrict__ A, int ldA, long sAz,
             const u16* __restrict__ B, int ldB, long sBz,
             int K, Epi epi)
{
  __shared__ __align__(16) u16 As[128][32];
  __shared__ __align__(16) u16 Bs[128][32];
  const int bn = blockIdx.x, bm = blockIdx.y, bz = blockIdx.z;
  const int tid  = threadIdx.x;
  const int lane = tid & 63;
  const int wave = tid >> 6;
  const int wm = (wave & 1) << 6;
  const int wn = (wave >> 1) << 6;
  const int mrow = lane & 15;
  const int quad = lane >> 4;

  const u16* Ab = A + (long)bz*sAz + (long)bm*128*ldA;
  const u16* Bb = B + (long)bz*sBz + (long)bn*128*ldB;
  const int srow = tid >> 2;
  const int scol = (tid & 3) << 3;
  const u16* gA0 = Ab + (long)srow*ldA + scol;
  const u16* gA1 = Ab + (long)(srow+64)*ldA + scol;
  const u16* gB0 = Bb + (long)srow*ldB + scol;
  const u16* gB1 = Bb + (long)(srow+64)*ldB + scol;
  u16* lA0 = &As[srow][scol];
  u16* lA1 = &As[srow+64][scol];
  u16* lB0 = &Bs[srow][scol];
  u16* lB1 = &Bs[srow+64][scol];

  floatx4 acc[4][4];
#pragma unroll
  for (int i=0;i<4;i++)
#pragma unroll
    for (int j=0;j<4;j++) acc[i][j] = 0.f;

  for (int k0 = 0; k0 < K; k0 += 32) {
    GLOAD16(lA0, gA0); GLOAD16(lA1, gA1);
    GLOAD16(lB0, gB0); GLOAD16(lB1, gB1);
    gA0 += 32; gA1 += 32; gB0 += 32; gB1 += 32;
    asm volatile("s_waitcnt vmcnt(0)" ::: "memory");
    __syncthreads();
    bf16x8 af[4], bfr[4];
#pragma unroll
    for (int i=0;i<4;i++) af[i]  = *(const bf16x8*)&As[wm + i*16 + mrow][quad*8];
#pragma unroll
    for (int i=0;i<4;i++) bfr[i] = *(const bf16x8*)&Bs[wn + i*16 + mrow][quad*8];
#pragma unroll
    for (int mi=0;mi<4;mi++)
#pragma unroll
      for (int ni=0;ni<4;ni++)
        acc[mi][ni] = __builtin_amdgcn_mfma_f32_16x16x32_bf16(af[mi], bfr[ni], acc[mi][ni], 0,0,0);
    __syncthreads();
  }

#pragma unroll
  for (int mi=0;mi<4;mi++)
#pragma unroll
    for (int ni=0;ni<4;ni++) {
      const int col  = (bn<<7) + wn + ni*16 + mrow;
      const int row0 = (bm<<7) + wm + mi*16 + quad*4;
#pragma unroll
      for (int r=0;r<4;r++)
        epi(row0 + r, col, bz, acc[mi][ni][r]);
    }
}

// ---------------------------------------------------------------------------
// Typed linear with row gather: C rows are gathered by type, scatter on write.
// A = cn_nodes [8192][512]; B = Wio_t[t][1024][512]; grid (8, 64, 3).
// ---------------------------------------------------------------------------
__global__ __launch_bounds__(256)
void gemm_typed(const u16* __restrict__ A, const u16* __restrict__ B,
                const int* __restrict__ idx, const int* __restrict__ cnt,
                u16* __restrict__ node_in, u16* __restrict__ node_out)
{
  const int bz = blockIdx.z;
  const int count = cnt[bz];
  const int m0 = blockIdx.y << 7;
  if (m0 >= count) return;
  __shared__ __align__(16) u16 As[128][32];
  __shared__ __align__(16) u16 Bs[128][32];
  const int bn = blockIdx.x;
  const int tid  = threadIdx.x;
  const int lane = tid & 63;
  const int wave = tid >> 6;
  const int wm = (wave & 1) << 6;
  const int wn = (wave >> 1) << 6;
  const int mrow = lane & 15;
  const int quad = lane >> 4;
  const int* myidx = idx + bz*8192;

  const int srow = tid >> 2;
  const int scol = (tid & 3) << 3;
  int r0i = m0 + srow;      if (r0i >= count) r0i = m0;
  int r1i = m0 + srow + 64; if (r1i >= count) r1i = m0;
  const u16* gA0 = A + (long)myidx[r0i]*512 + scol;
  const u16* gA1 = A + (long)myidx[r1i]*512 + scol;
  const u16* Bb = B + (long)bz*1024*512 + (long)bn*128*512;
  const u16* gB0 = Bb + (long)srow*512 + scol;
  const u16* gB1 = Bb + (long)(srow+64)*512 + scol;
  u16* lA0 = &As[srow][scol];
  u16* lA1 = &As[srow+64][scol];
  u16* lB0 = &Bs[srow][scol];
  u16* lB1 = &Bs[srow+64][scol];

  floatx4 acc[4][4];
#pragma unroll
  for (int i=0;i<4;i++)
#pragma unroll
    for (int j=0;j<4;j++) acc[i][j] = 0.f;

  for (int k0 = 0; k0 < 512; k0 += 32) {
    GLOAD16(lA0, gA0); GLOAD16(lA1, gA1);
    GLOAD16(lB0, gB0); GLOAD16(lB1, gB1);
    gA0 += 32; gA1 += 32; gB0 += 32; gB1 += 32;
    asm volatile("s_waitcnt vmcnt(0)" ::: "memory");
    __syncthreads();
    bf16x8 af[4], bfr[4];
#pragma unroll
    for (int i=0;i<4;i++) af[i]  = *(const bf16x8*)&As[wm + i*16 + mrow][quad*8];
#pragma unroll
    for (int i=0;i<4;i++) bfr[i] = *(const bf16x8*)&Bs[wn + i*16 + mrow][quad*8];
#pragma unroll
    for (int mi=0;mi<4;mi++)
#pragma unroll
      for (int ni=0;ni<4;ni++)
        acc[mi][ni] = __builtin_amdgcn_mfma_f32_16x16x32_bf16(af[mi], bfr[ni], acc[mi][ni], 0,0,0);
    __syncthreads();
  }

#pragma unroll
  for (int mi=0;mi<4;mi++) {
    const int lr0 = wm + mi*16 + quad*4;
#pragma unroll
    for (int r=0;r<4;r++) {
      const int lr = lr0 + r;
      if (m0 + lr >= count) continue;
      const long orig = myidx[m0 + lr];
#pragma unroll
      for (int ni=0;ni<4;ni++) {
        const int col = (bn<<7) + wn + ni*16 + mrow;
        u16 h = f2bf(acc[mi][ni][r]);
        if (col < 512) node_in [orig*512 + col]       = h;
        else           node_out[orig*512 + (col-512)] = h;
      }
    }
  }
}

// --- epilogues --------------------------------------------------------------
struct EpiPV {      // bz = batch; scale row by inv_l, write into X (ld 2048)
  const float* inv_l; u16* X; int colOff;
  __device__ void operator()(int row, int col, int bz, float v) const {
    long gr = (long)bz*1024 + row;
    X[gr*2048 + colOff + col] = f2bf(v * inv_l[gr]);
  }
};
struct EpiG1 {      // col<512: rn -> X[:,1536+col]; else z -> zbuf (bf16)
  const u16* nodes; const u16* b_r; const u16* b_z; u16* X; u16* zbuf;
  __device__ void operator()(int row, int col, int bz, float v) const {
    if (col < 512) {
      float r = sigm(v + bf2f(b_r[col]));
      X[(long)row*2048 + 1536 + col] = f2bf(r * bf2f(nodes[(long)row*512 + col]));
    } else {
      int c = col - 512;
      zbuf[(long)row*512 + c] = f2bf(sigm(v + bf2f(b_z[c])));
    }
  }
};
struct EpiG2 {      // h_hat = tanh(v + b_t); out = (1-z)n + z h_hat
  const u16* zbuf; const u16* nodes; const u16* b_t; const int* flags; void* out;
  __device__ void operator()(int row, int col, int bz, float v) const {
    long idx = (long)row*512 + col;
    float t = fminf(fmaxf(v + bf2f(b_t[col]), -15.f), 15.f);
    float h = tanhf(t);
    float z = bf2f(zbuf[idx]);
    float nv = bf2f(nodes[idx]);
    float o2 = (1.f - z)*nv + z*h;
    if (flags[0]) ((float*)out)[idx] = o2;
    else          ((u16*)out)[idx]   = f2bf(o2);
  }
};

// --- generic tiled bf16 transpose ------------------------------------------
__global__ __launch_bounds__(256)
void k_transpose(u16* __restrict__ dst, int ldD, long dzs,
                 const u16* __restrict__ src, int ldS, long szs)
{
  __shared__ u16 tile[32][33];
  src += (long)blockIdx.z * szs;
  dst += (long)blockIdx.z * dzs;
  const int c0 = blockIdx.x*32, r0 = blockIdx.y*32;
  const int tx = threadIdx.x, ty = threadIdx.y;
#pragma unroll
  for (int i=0;i<32;i+=8)
    tile[ty+i][tx] = src[(long)(r0+ty+i)*ldS + c0 + tx];
  __syncthreads();
#pragma unroll
  for (int i=0;i<32;i+=8)
    dst[(long)(c0+ty+i)*ldD + r0 + tx] = tile[tx][ty+i];
}

// --- rotated weight transpose: dst[n][(r+rot)%1536] = src[r][n], src 1536x512
struct TrDesc { const u16* src[3]; u16* dst[3]; int rot[3]; };
__global__ __launch_bounds__(256)
void k_wtrans(TrDesc d)
{
  __shared__ u16 tile[32][33];
  const int z = blockIdx.z;
  const u16* src = d.src[z];
  u16* dst = d.dst[z];
  const int c0 = blockIdx.x*32, r0 = blockIdx.y*32;
  const int tx = threadIdx.x, ty = threadIdx.y;
#pragma unroll
  for (int i=0;i<32;i+=8)
    tile[ty+i][tx] = src[(long)(r0+ty+i)*512 + c0 + tx];
  __syncthreads();
  const int k0 = (r0 + d.rot[z]) % 1536;
#pragma unroll
  for (int i=0;i<32;i+=8)
    dst[(long)(c0+ty+i)*1536 + k0 + tx] = tile[tx][ty+i];
}

// --- merged V transposes: node_in/node_out [b][1024][512] -> Vt [b][512][1024]
__global__ __launch_bounds__(256)
void k_vtrans(const u16* __restrict__ nin, const u16* __restrict__ nout,
              u16* __restrict__ vin, u16* __restrict__ vout)
{
  __shared__ u16 tile[32][33];
  const int z = blockIdx.z;
  const int b = z & 7;
  const u16* src = (z < 8 ? nin : nout) + (long)b*1024*512;
  u16* dst = (z < 8 ? vin : vout) + (long)b*512*1024;
  const int c0 = blockIdx.x*32, r0 = blockIdx.y*32;
  const int tx = threadIdx.x, ty = threadIdx.y;
#pragma unroll
  for (int i=0;i<32;i+=8)
    tile[ty+i][tx] = src[(long)(r0+ty+i)*512 + c0 + tx];
  __syncthreads();
#pragma unroll
  for (int i=0;i<32;i+=8)
    dst[(long)(c0+ty+i)*1024 + r0 + tx] = tile[tx][ty+i];
}

// --- copy nodes into X[:,0:512) (ld 2048) ----------------------------------
__global__ __launch_bounds__(256)
void k_copyX(const u16* __restrict__ nodes, u16* __restrict__ X)
{
  long idx = (long)blockIdx.x*256 + threadIdx.x;
  long r = idx >> 6;
  int  c = (int)(idx & 63) << 3;
  *(uint4*)&X[r*2048 + c] = *(const uint4*)&nodes[r*512 + c];
}

__device__ __forceinline__ void load8f(float* f, const u16* p){
  uint4 q = *(const uint4*)p;
  unsigned w[4] = {q.x, q.y, q.z, q.w};
#pragma unroll
  for (int i=0;i<4;i++){ f[2*i] = bf2f((u16)(w[i]&0xffffu)); f[2*i+1] = bf2f((u16)(w[i]>>16)); }
}

// --- per-row scalar projections --------------------------------------------
__global__ __launch_bounds__(256)
void k_svec(const u16* __restrict__ nodes, const u16* __restrict__ nin, const u16* __restrict__ nout,
            const u16* __restrict__ aiq, const u16* __restrict__ aiv,
            const u16* __restrict__ aoq, const u16* __restrict__ aov,
            float* sq_in, float* sq_out, float* sv_in, float* sv_out)
{
  const int lane = threadIdx.x & 63, wave = threadIdx.x >> 6;
  const long row = (long)blockIdx.x*4 + wave;
  const int c = lane << 3;
  float xn[8], xi[8], xo[8], q1[8], v1[8], q2[8], v2[8];
  load8f(xn, nodes + row*512 + c);
  load8f(xi, nin   + row*512 + c);
  load8f(xo, nout  + row*512 + c);
  load8f(q1, aiq + c); load8f(v1, aiv + c);
  load8f(q2, aoq + c); load8f(v2, aov + c);
  float s0=0,s1=0,s2=0,s3=0;
#pragma unroll
  for (int j=0;j<8;j++){ s0 += xn[j]*q1[j]; s1 += xn[j]*q2[j]; s2 += xi[j]*v1[j]; s3 += xo[j]*v2[j]; }
#pragma unroll
  for (int off=32; off; off>>=1){
    s0 += __shfl_xor(s0, off);
    s1 += __shfl_xor(s1, off);
    s2 += __shfl_xor(s2, off);
    s3 += __shfl_xor(s3, off);
  }
  if (lane==0){ sq_in[row]=s0; sq_out[row]=s1; sv_in[row]=s2; sv_out[row]=s3; }
}

// --- masked-softmax stats + materialize P (bf16) ---------------------------
__global__ __launch_bounds__(256)
void k_stats(const int* __restrict__ mask, const float* __restrict__ sq,
             const float* __restrict__ sv, u16* __restrict__ P, float* __restrict__ inv_l)
{
  const int lane = threadIdx.x & 63, wave = threadIdx.x >> 6;
  const long row = (long)blockIdx.x*4 + wave;
  const long b = row >> 10;
  const int* mrow = mask + row*1024;
  const float* svb = sv + b*1024;
  const float qs = sq[row];
  float m = -3.0e38f;
#pragma unroll
  for (int it=0; it<8; ++it) {
    int j = it*128 + lane*2;
    int2 mk = *(const int2*)&mrow[j];
    float2 s = *(const float2*)&svb[j];
    float e0 = mk.x > 0 ? lrelu(qs + s.x) : -1e9f;
    float e1 = mk.y > 0 ? lrelu(qs + s.y) : -1e9f;
    m = fmaxf(m, fmaxf(e0, e1));
  }
#pragma unroll
  for (int off=32; off; off>>=1) m = fmaxf(m, __shfl_xor(m, off));
  float l = 0.f;
#pragma unroll
  for (int it=0; it<8; ++it) {
    int j = it*128 + lane*2;
    int2 mk = *(const int2*)&mrow[j];
    float2 s = *(const float2*)&svb[j];
    float e0 = mk.x > 0 ? lrelu(qs + s.x) : -1e9f;
    float e1 = mk.y > 0 ? lrelu(qs + s.y) : -1e9f;
    float p0 = expf(e0 - m), p1 = expf(e1 - m);
    *(unsigned*)&P[row*1024 + j] = (unsigned)f2bf(p0) | ((unsigned)f2bf(p1) << 16);
    l += p0 + p1;
  }
#pragma unroll
  for (int off=32; off; off>>=1) l += __shfl_xor(l, off);
  if (lane==0) inv_l[row] = 1.f / l;
}

// ---------------------------------------------------------------------------
extern "C" void kernel_launch(void* const* d_in, const int* in_sizes, int n_in,
                              void* d_out, int out_size, void* d_ws, size_t ws_size,
                              hipStream_t stream)
{
  const void* nodes_r   = d_in[0];
  const int*  mask      = (const int*)d_in[1];
  const int*  ntype     = (const int*)d_in[2];

  char* base = (char*)d_ws;
  size_t o = 0;
  auto alloc = [&](size_t bytes){ void* p = base + o; o += (bytes + 255) & ~size_t(255); return p; };
  int*  flags   = (int*)alloc(256);
  int*  cnt     = (int*)alloc(256);
  int*  idx     = (int*)alloc(3ll*8192*4);
  u16* cn_nodes = (u16*)alloc(8192ll*512*2);
  u16* cn_Win   = (u16*)alloc(3ll*512*512*2);
  u16* cn_Wout  = (u16*)alloc(3ll*512*512*2);
  u16* cn_Wr    = (u16*)alloc(1536ll*512*2);
  u16* cn_Wz    = (u16*)alloc(1536ll*512*2);
  u16* cn_Wt    = (u16*)alloc(1536ll*512*2);
  u16* cn_aiq   = (u16*)alloc(512*2);
  u16* cn_aiv   = (u16*)alloc(512*2);
  u16* cn_aoq   = (u16*)alloc(512*2);
  u16* cn_aov   = (u16*)alloc(512*2);
  u16* cn_br    = (u16*)alloc(512*2);
  u16* cn_bz    = (u16*)alloc(512*2);
  u16* cn_bt    = (u16*)alloc(512*2);
  u16* node_in  = (u16*)alloc(8192ll*512*2);   // zbuf aliases this after svec
  u16* node_out = (u16*)alloc(8192ll*512*2);   // adjacent (joint memset)
  u16* VtIn     = (u16*)alloc(8ll*512*1024*2);
  u16* VtOut    = (u16*)alloc(8ll*512*1024*2);
  u16* X        = (u16*)alloc(8192ll*2048*2);  // [nodes|h_in|h_out|rn], ld 2048
  u16* P        = (u16*)alloc(8ll*1024*1024*2);
  u16* Wio_t    = (u16*)alloc(3ll*1024*512*2);
  u16* Wrz_t    = (u16*)alloc(1024ll*1536*2);
  u16* Wt_t     = (u16*)alloc(512ll*1536*2);
  float* sq_in  = (float*)alloc(8192*4);
  float* sq_out = (float*)alloc(8192*4);
  float* sv_in  = (float*)alloc(8192*4);
  float* sv_out = (float*)alloc(8192*4);
  float* il_in  = (float*)alloc(8192*4);
  float* il_out = (float*)alloc(8192*4);
  u16* zbuf = node_in;   // alias: node_in last read by k_svec, zbuf written at G1

  hipMemsetAsync(node_in, 0, 2ll*8192*512*2, stream);   // node_in + node_out

  k_detect<<<1, 256, 0, stream>>>((const u16*)nodes_r, ntype, flags);

  // merged canon of 13 tensors
  CanonDesc cd;
  const int canonN[13] = {8192*512, 3*512*512, 3*512*512, 1536*512, 1536*512, 1536*512,
                          512,512,512,512,512,512,512};
  u16* canonDst[13] = {cn_nodes, cn_Win, cn_Wout, cn_Wr, cn_Wz, cn_Wt,
                       cn_aiq, cn_aiv, cn_aoq, cn_aov, cn_br, cn_bz, cn_bt};
  const int canonSrcIdx[13] = {0,3,4,9,11,13,5,6,7,8,10,12,14};
  int blk = 0;
  for (int s=0;s<13;s++){
    cd.src[s] = d_in[canonSrcIdx[s]];
    cd.dst[s] = canonDst[s];
    cd.n4[s]  = canonN[s]/4;
    cd.startBlk[s] = blk;
    blk += (cd.n4[s] + 255)/256;
  }
  k_canon_all<<<blk, 256, 0, stream>>>(cd, flags);

  k_build_idx<<<1, 256, 0, stream>>>(ntype, flags, idx, cnt);

  // weight transposes
  TrDesc td;
  td.src[0]=cn_Wr; td.src[1]=cn_Wz; td.src[2]=cn_Wt;
  td.dst[0]=Wrz_t; td.dst[1]=Wrz_t + 512ll*1536; td.dst[2]=Wt_t;
  td.rot[0]=512; td.rot[1]=512; td.rot[2]=0;
  k_wtrans<<<dim3(16,48,3), dim3(32,8), 0, stream>>>(td);
  dim3 tb(32,8);
  k_transpose<<<dim3(16,16,3), tb, 0, stream>>>(Wio_t,             512, 1024ll*512, cn_Win,  512, 512ll*512);
  k_transpose<<<dim3(16,16,3), tb, 0, stream>>>(Wio_t + 512ll*512, 512, 1024ll*512, cn_Wout, 512, 512ll*512);

  // typed linear, gathered rows
  gemm_typed<<<dim3(8,64,3), 256, 0, stream>>>(cn_nodes, Wio_t, idx, cnt, node_in, node_out);

  // V^T for PV B-operands (merged)
  k_vtrans<<<dim3(16,32,16), tb, 0, stream>>>(node_in, node_out, VtIn, VtOut);

  k_svec<<<2048, 256, 0, stream>>>(cn_nodes, node_in, node_out, cn_aiq, cn_aiv, cn_aoq, cn_aov,
                                   sq_in, sq_out, sv_in, sv_out);
  k_copyX<<<2048, 256, 0, stream>>>(cn_nodes, X);

  // GAT in -> X[:,512:1024)
  k_stats<<<2048, 256, 0, stream>>>(mask, sq_in, sv_in, P, il_in);
  gemm_bt<<<dim3(4,8,8), 256, 0, stream>>>(P, 1024, 1024ll*1024, VtIn, 1024, 512ll*1024, 1024,
                                           EpiPV{il_in, X, 512});
  // GAT out -> X[:,1024:1536)
  k_stats<<<2048, 256, 0, stream>>>(mask + 8ll*1024*1024, sq_out, sv_out, P, il_out);
  gemm_bt<<<dim3(4,8,8), 256, 0, stream>>>(P, 1024, 1024ll*1024, VtOut, 1024, 512ll*1024, 1024,
                                           EpiPV{il_out, X, 1024});

  // GGNN G1: [nodes|h_in|h_out] @ [W_r|W_z] (k-rotated) -> rn into X[:,1536:2048), z
  gemm_bt<<<dim3(8,64,1), 256, 0, stream>>>(X, 2048, 0ll, Wrz_t, 1536, 0ll, 1536,
                                            EpiG1{cn_nodes, cn_br, cn_bz, X, zbuf});
  // GGNN G2: [h_in|h_out|rn] @ W_t -> gated output
  gemm_bt<<<dim3(4,64,1), 256, 0, stream>>>(X + 512, 2048, 0ll, Wt_t, 1536, 0ll, 1536,
                                            EpiG2{zbuf, cn_nodes, cn_bt, flags, (void*)d_out});
}

// Round 4
// 397.389 us; speedup vs baseline: 1.2051x; 1.0957x over previous
//
#include <hip/hip_runtime.h>
#include <hip/hip_bf16.h>
#include <stdint.h>

typedef unsigned short u16;
typedef __attribute__((ext_vector_type(8))) short bf16x8;
typedef __attribute__((ext_vector_type(4))) float floatx4;

__device__ __forceinline__ float bf2f(u16 v){ return __uint_as_float(((unsigned)v)<<16); }
__device__ __forceinline__ u16 f2bf(float f){
  unsigned u = __float_as_uint(f);
  unsigned r = 0x7fffu + ((u>>16)&1u);
  return (u16)((u+r)>>16);
}
__device__ __forceinline__ float lrelu(float x){ return x > 0.f ? x : 0.2f*x; }
__device__ __forceinline__ float sigm(float t){
  t = fminf(fmaxf(t, -30.f), 30.f);
  return 1.f/(1.f + expf(-t));
}

#define GLOAD16(ldsdst, gsrc) \
  __builtin_amdgcn_global_load_lds((const __attribute__((address_space(1))) void*)(gsrc), \
      (__attribute__((address_space(3))) void*)(ldsdst), 16, 0, 0)

// ---------------------------------------------------------------------------
// dtype detector: flags[0]=1 -> float inputs are f32; flags[1]=1 -> node_type int64
// ---------------------------------------------------------------------------
__global__ void k_detect(const u16* __restrict__ nodes_raw,
                         const int* __restrict__ ntype_raw, int* flags)
{
  __shared__ int s_wild, s_nz;
  if (threadIdx.x == 0){ s_wild = 0; s_nz = 0; }
  __syncthreads();
  int wild = 0;
#pragma unroll
  for (int i = 0; i < 16; i++){
    u16 w = nodes_raw[threadIdx.x*16 + i];
    int e = (w >> 7) & 0xFF;
    if (e != 0 && (e < 102 || e > 152)) wild++;
  }
  int nz = 0;
  if (threadIdx.x < 255 && ntype_raw[2*threadIdx.x + 1] != 0) nz = 1;
  atomicAdd(&s_wild, wild);
  atomicAdd(&s_nz, nz);
  __syncthreads();
  if (threadIdx.x == 0){
    flags[0] = (s_wild > 1024) ? 1 : 0;
    flags[1] = (s_nz == 0) ? 1 : 0;
  }
}

// --- merged canonicalization of all 13 float tensors (+ nodes into X) ------
struct CanonDesc {
  const void* src[13];
  u16*        dst[13];
  int startBlk[13];
  int n4[13];
};
__global__ __launch_bounds__(256)
void k_canon_all(CanonDesc d, u16* __restrict__ X, const int* __restrict__ flags)
{
  int blk = blockIdx.x;
  int seg = 0;
#pragma unroll
  for (int s = 1; s < 13; s++) if (blk >= d.startBlk[s]) seg = s;
  int i = (blk - d.startBlk[seg])*256 + threadIdx.x;
  if (i >= d.n4[seg]) return;
  uint2 bits;
  if (flags[0]) {
    float4 v = ((const float4*)d.src[seg])[i];
    ushort4 o2;
    o2.x = f2bf(v.x); o2.y = f2bf(v.y); o2.z = f2bf(v.z); o2.w = f2bf(v.w);
    bits = *(uint2*)&o2;
  } else {
    bits = ((const uint2*)d.src[seg])[i];
  }
  ((uint2*)d.dst[seg])[i] = bits;
  if (seg == 0) {               // nodes also -> X[:,0:512), ld 2048
    int e0 = i*4;
    long r = e0 >> 9;
    int  c = e0 & 511;
    *(uint2*)&X[r*2048 + c] = bits;
  }
}

// --- per-type row index lists ----------------------------------------------
__global__ void k_build_idx(const int* __restrict__ ntype, const int* __restrict__ flags,
                            int* __restrict__ idx, int* __restrict__ cnt)
{
  __shared__ int c[3];
  if (threadIdx.x < 3) c[threadIdx.x] = 0;
  __syncthreads();
  const int i64 = flags[1];
  for (int i = threadIdx.x; i < 8192; i += 256){
    int t = i64 ? ntype[2*i] : ntype[i];
    if (t >= 2 && t <= 4){
      int p = atomicAdd(&c[t-2], 1);
      idx[(t-2)*8192 + p] = i;
    }
  }
  __syncthreads();
  if (threadIdx.x < 3) cnt[threadIdx.x] = c[threadIdx.x];
}

// ---------------------------------------------------------------------------
// 128x128 bf16 GEMM, C = A(MxK) * B^T, double-buffered LDS, 1 barrier/iter.
// MODE 0: bm=bx (XCD-fast = M stripes), bn=by, bz=bzi.
// MODE 1: bz=bx (XCD-fast = batch),     bn=by, bm=bzi.
// ---------------------------------------------------------------------------
template<int MODE, class Epi>
__global__ __launch_bounds__(256)
void gemm_bt(const u16* __restrict__ A, int ldA, long sAz,
             const u16* __restrict__ B, int ldB, long sBz,
             int K, Epi epi)
{
  __shared__ __align__(16) u16 As[2][128][32];
  __shared__ __align__(16) u16 Bs[2][128][32];
  int bm, bn, bz;
  if (MODE == 0){ bm = blockIdx.x; bn = blockIdx.y; bz = blockIdx.z; }
  else          { bz = blockIdx.x; bn = blockIdx.y; bm = blockIdx.z; }
  const int tid  = threadIdx.x;
  const int lane = tid & 63;
  const int wave = tid >> 6;
  const int wm = (wave & 1) << 6;
  const int wn = (wave >> 1) << 6;
  const int mrow = lane & 15;
  const int quad = lane >> 4;

  const u16* Ab = A + (long)bz*sAz + (long)bm*128*ldA;
  const u16* Bb = B + (long)bz*sBz + (long)bn*128*ldB;
  const int srow = tid >> 2;
  const int scol = (tid & 3) << 3;
  const u16* gA0 = Ab + (long)srow*ldA + scol;
  const u16* gA1 = Ab + (long)(srow+64)*ldA + scol;
  const u16* gB0 = Bb + (long)srow*ldB + scol;
  const u16* gB1 = Bb + (long)(srow+64)*ldB + scol;

  floatx4 acc[4][4];
#pragma unroll
  for (int i=0;i<4;i++)
#pragma unroll
    for (int j=0;j<4;j++) acc[i][j] = 0.f;

  auto issue = [&](int buf){
    GLOAD16(&As[buf][srow][scol],    gA0);
    GLOAD16(&As[buf][srow+64][scol], gA1);
    GLOAD16(&Bs[buf][srow][scol],    gB0);
    GLOAD16(&Bs[buf][srow+64][scol], gB1);
    gA0 += 32; gA1 += 32; gB0 += 32; gB1 += 32;
  };

  issue(0);
  const int nIter = K >> 5;
  for (int it = 0; it < nIter; ++it) {
    const int cur = it & 1;
    asm volatile("s_waitcnt vmcnt(0)" ::: "memory");
    __syncthreads();
    if (it + 1 < nIter) issue(cur ^ 1);
    bf16x8 af[4], bfr[4];
#pragma unroll
    for (int i=0;i<4;i++) af[i]  = *(const bf16x8*)&As[cur][wm + i*16 + mrow][quad*8];
#pragma unroll
    for (int i=0;i<4;i++) bfr[i] = *(const bf16x8*)&Bs[cur][wn + i*16 + mrow][quad*8];
#pragma unroll
    for (int mi=0;mi<4;mi++)
#pragma unroll
      for (int ni=0;ni<4;ni++)
        acc[mi][ni] = __builtin_amdgcn_mfma_f32_16x16x32_bf16(af[mi], bfr[ni], acc[mi][ni], 0,0,0);
  }

  // C/D layout: col = lane&15, row = quad*4 + reg  [m89/m91]
#pragma unroll
  for (int mi=0;mi<4;mi++)
#pragma unroll
    for (int ni=0;ni<4;ni++) {
      const int col  = (bn<<7) + wn + ni*16 + mrow;
      const int row0 = (bm<<7) + wm + mi*16 + quad*4;
#pragma unroll
      for (int r=0;r<4;r++)
        epi(row0 + r, col, bz, acc[mi][ni][r]);
    }
}

// ---------------------------------------------------------------------------
// Typed linear with row gather (double-buffered, M-fast grid: x=bm,y=bn,z=t)
// ---------------------------------------------------------------------------
__global__ __launch_bounds__(256)
void gemm_typed(const u16* __restrict__ A, const u16* __restrict__ B,
                const int* __restrict__ idx, const int* __restrict__ cnt,
                u16* __restrict__ node_in, u16* __restrict__ node_out)
{
  const int bz = blockIdx.z;
  const int count = cnt[bz];
  const int m0 = blockIdx.x << 7;
  if (m0 >= count) return;
  __shared__ __align__(16) u16 As[2][128][32];
  __shared__ __align__(16) u16 Bs[2][128][32];
  const int bn = blockIdx.y;
  const int tid  = threadIdx.x;
  const int lane = tid & 63;
  const int wave = tid >> 6;
  const int wm = (wave & 1) << 6;
  const int wn = (wave >> 1) << 6;
  const int mrow = lane & 15;
  const int quad = lane >> 4;
  const int* myidx = idx + bz*8192;

  const int srow = tid >> 2;
  const int scol = (tid & 3) << 3;
  int r0i = m0 + srow;      if (r0i >= count) r0i = m0;
  int r1i = m0 + srow + 64; if (r1i >= count) r1i = m0;
  const u16* gA0 = A + (long)myidx[r0i]*512 + scol;
  const u16* gA1 = A + (long)myidx[r1i]*512 + scol;
  const u16* Bb = B + (long)bz*1024*512 + (long)bn*128*512;
  const u16* gB0 = Bb + (long)srow*512 + scol;
  const u16* gB1 = Bb + (long)(srow+64)*512 + scol;

  floatx4 acc[4][4];
#pragma unroll
  for (int i=0;i<4;i++)
#pragma unroll
    for (int j=0;j<4;j++) acc[i][j] = 0.f;

  auto issue = [&](int buf){
    GLOAD16(&As[buf][srow][scol],    gA0);
    GLOAD16(&As[buf][srow+64][scol], gA1);
    GLOAD16(&Bs[buf][srow][scol],    gB0);
    GLOAD16(&Bs[buf][srow+64][scol], gB1);
    gA0 += 32; gA1 += 32; gB0 += 32; gB1 += 32;
  };

  issue(0);
  for (int it = 0; it < 16; ++it) {
    const int cur = it & 1;
    asm volatile("s_waitcnt vmcnt(0)" ::: "memory");
    __syncthreads();
    if (it + 1 < 16) issue(cur ^ 1);
    bf16x8 af[4], bfr[4];
#pragma unroll
    for (int i=0;i<4;i++) af[i]  = *(const bf16x8*)&As[cur][wm + i*16 + mrow][quad*8];
#pragma unroll
    for (int i=0;i<4;i++) bfr[i] = *(const bf16x8*)&Bs[cur][wn + i*16 + mrow][quad*8];
#pragma unroll
    for (int mi=0;mi<4;mi++)
#pragma unroll
      for (int ni=0;ni<4;ni++)
        acc[mi][ni] = __builtin_amdgcn_mfma_f32_16x16x32_bf16(af[mi], bfr[ni], acc[mi][ni], 0,0,0);
  }

#pragma unroll
  for (int mi=0;mi<4;mi++) {
    const int lr0 = wm + mi*16 + quad*4;
#pragma unroll
    for (int r=0;r<4;r++) {
      const int lr = lr0 + r;
      if (m0 + lr >= count) continue;
      const long orig = myidx[m0 + lr];
#pragma unroll
      for (int ni=0;ni<4;ni++) {
        const int col = (bn<<7) + wn + ni*16 + mrow;
        u16 h = f2bf(acc[mi][ni][r]);
        if (col < 512) node_in [orig*512 + col]       = h;
        else           node_out[orig*512 + (col-512)] = h;
      }
    }
  }
}

// --- epilogues --------------------------------------------------------------
struct EpiPV {      // bz = batch; scale row by inv_l, write into X (ld 2048)
  const float* inv_l; u16* X; int colOff;
  __device__ void operator()(int row, int col, int bz, float v) const {
    long gr = (long)bz*1024 + row;
    X[gr*2048 + colOff + col] = f2bf(v * inv_l[gr]);
  }
};
struct EpiG1 {      // col<512: rn -> X[:,1536+col]; else z -> zbuf (bf16)
  const u16* nodes; const u16* b_r; const u16* b_z; u16* X; u16* zbuf;
  __device__ void operator()(int row, int col, int bz, float v) const {
    if (col < 512) {
      float r = sigm(v + bf2f(b_r[col]));
      X[(long)row*2048 + 1536 + col] = f2bf(r * bf2f(nodes[(long)row*512 + col]));
    } else {
      int c = col - 512;
      zbuf[(long)row*512 + c] = f2bf(sigm(v + bf2f(b_z[c])));
    }
  }
};
struct EpiG2 {      // h_hat = tanh(v + b_t); out = (1-z)n + z h_hat
  const u16* zbuf; const u16* nodes; const u16* b_t; const int* flags; void* out;
  __device__ void operator()(int row, int col, int bz, float v) const {
    long idx = (long)row*512 + col;
    float t = fminf(fmaxf(v + bf2f(b_t[col]), -15.f), 15.f);
    float h = tanhf(t);
    float z = bf2f(zbuf[idx]);
    float nv = bf2f(nodes[idx]);
    float o2 = (1.f - z)*nv + z*h;
    if (flags[0]) ((float*)out)[idx] = o2;
    else          ((u16*)out)[idx]   = f2bf(o2);
  }
};

// --- merged weight transposes: 9 slices ------------------------------------
// dst[c][ (r+rot) % modK ] = src[r][c]; src is rows x 512.
struct TrDesc {
  const u16* src[9]; u16* dst[9]; int rot[9]; int ldD[9]; int rows[9]; int modK[9];
};
__global__ __launch_bounds__(256)
void k_wtrans(TrDesc d)
{
  __shared__ u16 tile[32][33];
  const int z = blockIdx.z;
  const int r0 = blockIdx.y*32;
  if (r0 >= d.rows[z]) return;
  const u16* src = d.src[z];
  u16* dst = d.dst[z];
  const int c0 = blockIdx.x*32;
  const int tx = threadIdx.x, ty = threadIdx.y;
#pragma unroll
  for (int i=0;i<32;i+=8)
    tile[ty+i][tx] = src[(long)(r0+ty+i)*512 + c0 + tx];
  __syncthreads();
  const int k0 = (r0 + d.rot[z]) % d.modK[z];
#pragma unroll
  for (int i=0;i<32;i+=8)
    dst[(long)(c0+ty+i)*d.ldD[z] + k0 + tx] = tile[tx][ty+i];
}

// --- merged V transposes: node_in/node_out [b][1024][512] -> Vt [b][512][1024]
__global__ __launch_bounds__(256)
void k_vtrans(const u16* __restrict__ nin, const u16* __restrict__ nout,
              u16* __restrict__ vin, u16* __restrict__ vout)
{
  __shared__ u16 tile[32][33];
  const int z = blockIdx.z;
  const int b = z & 7;
  const u16* src = (z < 8 ? nin : nout) + (long)b*1024*512;
  u16* dst = (z < 8 ? vin : vout) + (long)b*512*1024;
  const int c0 = blockIdx.x*32, r0 = blockIdx.y*32;
  const int tx = threadIdx.x, ty = threadIdx.y;
#pragma unroll
  for (int i=0;i<32;i+=8)
    tile[ty+i][tx] = src[(long)(r0+ty+i)*512 + c0 + tx];
  __syncthreads();
#pragma unroll
  for (int i=0;i<32;i+=8)
    dst[(long)(c0+ty+i)*1024 + r0 + tx] = tile[tx][ty+i];
}

__device__ __forceinline__ void load8f(float* f, const u16* p){
  uint4 q = *(const uint4*)p;
  unsigned w[4] = {q.x, q.y, q.z, q.w};
#pragma unroll
  for (int i=0;i<4;i++){ f[2*i] = bf2f((u16)(w[i]&0xffffu)); f[2*i+1] = bf2f((u16)(w[i]>>16)); }
}

// --- per-row scalar projections --------------------------------------------
__global__ __launch_bounds__(256)
void k_svec(const u16* __restrict__ nodes, const u16* __restrict__ nin, const u16* __restrict__ nout,
            const u16* __restrict__ aiq, const u16* __restrict__ aiv,
            const u16* __restrict__ aoq, const u16* __restrict__ aov,
            float* sq_in, float* sq_out, float* sv_in, float* sv_out)
{
  const int lane = threadIdx.x & 63, wave = threadIdx.x >> 6;
  const long row = (long)blockIdx.x*4 + wave;
  const int c = lane << 3;
  float xn[8], xi[8], xo[8], q1[8], v1[8], q2[8], v2[8];
  load8f(xn, nodes + row*512 + c);
  load8f(xi, nin   + row*512 + c);
  load8f(xo, nout  + row*512 + c);
  load8f(q1, aiq + c); load8f(v1, aiv + c);
  load8f(q2, aoq + c); load8f(v2, aov + c);
  float s0=0,s1=0,s2=0,s3=0;
#pragma unroll
  for (int j=0;j<8;j++){ s0 += xn[j]*q1[j]; s1 += xn[j]*q2[j]; s2 += xi[j]*v1[j]; s3 += xo[j]*v2[j]; }
#pragma unroll
  for (int off=32; off; off>>=1){
    s0 += __shfl_xor(s0, off);
    s1 += __shfl_xor(s1, off);
    s2 += __shfl_xor(s2, off);
    s3 += __shfl_xor(s3, off);
  }
  if (lane==0){ sq_in[row]=s0; sq_out[row]=s1; sv_in[row]=s2; sv_out[row]=s3; }
}

// --- masked-softmax stats + materialize P (bf16) ---------------------------
__global__ __launch_bounds__(256)
void k_stats(const int* __restrict__ mask, const float* __restrict__ sq,
             const float* __restrict__ sv, u16* __restrict__ P, float* __restrict__ inv_l)
{
  const int lane = threadIdx.x & 63, wave = threadIdx.x >> 6;
  const long row = (long)blockIdx.x*4 + wave;
  const long b = row >> 10;
  const int* mrow = mask + row*1024;
  const float* svb = sv + b*1024;
  const float qs = sq[row];
  float m = -3.0e38f;
  float e[4][4];
#pragma unroll
  for (int it=0; it<4; ++it) {
    int j = it*256 + lane*4;
    int4 mk = *(const int4*)&mrow[j];
    float4 s = *(const float4*)&svb[j];
    e[it][0] = mk.x > 0 ? lrelu(qs + s.x) : -1e9f;
    e[it][1] = mk.y > 0 ? lrelu(qs + s.y) : -1e9f;
    e[it][2] = mk.z > 0 ? lrelu(qs + s.z) : -1e9f;
    e[it][3] = mk.w > 0 ? lrelu(qs + s.w) : -1e9f;
    m = fmaxf(m, fmaxf(fmaxf(e[it][0], e[it][1]), fmaxf(e[it][2], e[it][3])));
  }
#pragma unroll
  for (int off=32; off; off>>=1) m = fmaxf(m, __shfl_xor(m, off));
  float l = 0.f;
#pragma unroll
  for (int it=0; it<4; ++it) {
    int j = it*256 + lane*4;
    float p0 = expf(e[it][0] - m), p1 = expf(e[it][1] - m);
    float p2 = expf(e[it][2] - m), p3 = expf(e[it][3] - m);
    ushort4 pk;
    pk.x = f2bf(p0); pk.y = f2bf(p1); pk.z = f2bf(p2); pk.w = f2bf(p3);
    *(ushort4*)&P[row*1024 + j] = pk;
    l += (p0 + p1) + (p2 + p3);
  }
#pragma unroll
  for (int off=32; off; off>>=1) l += __shfl_xor(l, off);
  if (lane==0) inv_l[row] = 1.f / l;
}

// ---------------------------------------------------------------------------
extern "C" void kernel_launch(void* const* d_in, const int* in_sizes, int n_in,
                              void* d_out, int out_size, void* d_ws, size_t ws_size,
                              hipStream_t stream)
{
  const void* nodes_r   = d_in[0];
  const int*  mask      = (const int*)d_in[1];
  const int*  ntype     = (const int*)d_in[2];

  char* base = (char*)d_ws;
  size_t o = 0;
  auto alloc = [&](size_t bytes){ void* p = base + o; o += (bytes + 255) & ~size_t(255); return p; };
  int*  flags   = (int*)alloc(256);
  int*  cnt     = (int*)alloc(256);
  int*  idx     = (int*)alloc(3ll*8192*4);
  u16* cn_nodes = (u16*)alloc(8192ll*512*2);
  u16* cn_Win   = (u16*)alloc(3ll*512*512*2);
  u16* cn_Wout  = (u16*)alloc(3ll*512*512*2);
  u16* cn_Wr    = (u16*)alloc(1536ll*512*2);
  u16* cn_Wz    = (u16*)alloc(1536ll*512*2);
  u16* cn_Wt    = (u16*)alloc(1536ll*512*2);
  u16* cn_aiq   = (u16*)alloc(512*2);
  u16* cn_aiv   = (u16*)alloc(512*2);
  u16* cn_aoq   = (u16*)alloc(512*2);
  u16* cn_aov   = (u16*)alloc(512*2);
  u16* cn_br    = (u16*)alloc(512*2);
  u16* cn_bz    = (u16*)alloc(512*2);
  u16* cn_bt    = (u16*)alloc(512*2);
  u16* node_in  = (u16*)alloc(8192ll*512*2);   // zbuf aliases this after svec
  u16* node_out = (u16*)alloc(8192ll*512*2);   // adjacent (joint memset)
  u16* VtIn     = (u16*)alloc(8ll*512*1024*2);
  u16* VtOut    = (u16*)alloc(8ll*512*1024*2);
  u16* X        = (u16*)alloc(8192ll*2048*2);  // [nodes|h_in|h_out|rn], ld 2048
  u16* P        = (u16*)alloc(8ll*1024*1024*2);
  u16* Wio_t    = (u16*)alloc(3ll*1024*512*2);
  u16* Wrz_t    = (u16*)alloc(1024ll*1536*2);
  u16* Wt_t     = (u16*)alloc(512ll*1536*2);
  float* sq_in  = (float*)alloc(8192*4);
  float* sq_out = (float*)alloc(8192*4);
  float* sv_in  = (float*)alloc(8192*4);
  float* sv_out = (float*)alloc(8192*4);
  float* il_in  = (float*)alloc(8192*4);
  float* il_out = (float*)alloc(8192*4);
  u16* zbuf = node_in;   // alias: node_in last read by k_svec, zbuf written at G1

  hipMemsetAsync(node_in, 0, 2ll*8192*512*2, stream);   // node_in + node_out

  k_detect<<<1, 256, 0, stream>>>((const u16*)nodes_r, ntype, flags);

  // merged canon of 13 tensors (+ nodes into X)
  CanonDesc cd;
  const int canonN[13] = {8192*512, 3*512*512, 3*512*512, 1536*512, 1536*512, 1536*512,
                          512,512,512,512,512,512,512};
  u16* canonDst[13] = {cn_nodes, cn_Win, cn_Wout, cn_Wr, cn_Wz, cn_Wt,
                       cn_aiq, cn_aiv, cn_aoq, cn_aov, cn_br, cn_bz, cn_bt};
  const int canonSrcIdx[13] = {0,3,4,9,11,13,5,6,7,8,10,12,14};
  int blk = 0;
  for (int s=0;s<13;s++){
    cd.src[s] = d_in[canonSrcIdx[s]];
    cd.dst[s] = canonDst[s];
    cd.n4[s]  = canonN[s]/4;
    cd.startBlk[s] = blk;
    blk += (cd.n4[s] + 255)/256;
  }
  k_canon_all<<<blk, 256, 0, stream>>>(cd, X, flags);

  k_build_idx<<<1, 256, 0, stream>>>(ntype, flags, idx, cnt);

  // merged weight transposes: Wr,Wz (rot 512 into Wrz_t), Wt (into Wt_t),
  // Win[0..2], Wout[0..2] (into Wio_t)
  TrDesc td;
  td.src[0]=cn_Wr; td.src[1]=cn_Wz; td.src[2]=cn_Wt;
  td.dst[0]=Wrz_t; td.dst[1]=Wrz_t + 512ll*1536; td.dst[2]=Wt_t;
  td.rot[0]=512; td.rot[1]=512; td.rot[2]=0;
  td.ldD[0]=1536; td.ldD[1]=1536; td.ldD[2]=1536;
  td.rows[0]=1536; td.rows[1]=1536; td.rows[2]=1536;
  td.modK[0]=1536; td.modK[1]=1536; td.modK[2]=1536;
  for (int t=0;t<3;t++){
    td.src[3+t]=cn_Win  + (long)t*512*512; td.dst[3+t]=Wio_t + (long)t*1024*512;
    td.src[6+t]=cn_Wout + (long)t*512*512; td.dst[6+t]=Wio_t + (long)t*1024*512 + 512ll*512;
    td.rot[3+t]=td.rot[6+t]=0; td.ldD[3+t]=td.ldD[6+t]=512;
    td.rows[3+t]=td.rows[6+t]=512; td.modK[3+t]=td.modK[6+t]=512;
  }
  k_wtrans<<<dim3(16,48,9), dim3(32,8), 0, stream>>>(td);

  // typed linear, gathered rows (x=bm for XCD spread)
  gemm_typed<<<dim3(64,8,3), 256, 0, stream>>>(cn_nodes, Wio_t, idx, cnt, node_in, node_out);

  // V^T for PV B-operands (merged)
  k_vtrans<<<dim3(16,32,16), dim3(32,8), 0, stream>>>(node_in, node_out, VtIn, VtOut);

  k_svec<<<2048, 256, 0, stream>>>(cn_nodes, node_in, node_out, cn_aiq, cn_aiv, cn_aoq, cn_aov,
                                   sq_in, sq_out, sv_in, sv_out);

  // GAT in -> X[:,512:1024)   (MODE 1: x=batch so each XCD owns one batch)
  k_stats<<<2048, 256, 0, stream>>>(mask, sq_in, sv_in, P, il_in);
  gemm_bt<1><<<dim3(8,4,8), 256, 0, stream>>>(P, 1024, 1024ll*1024, VtIn, 1024, 512ll*1024, 1024,
                                              EpiPV{il_in, X, 512});
  // GAT out -> X[:,1024:1536)
  k_stats<<<2048, 256, 0, stream>>>(mask + 8ll*1024*1024, sq_out, sv_out, P, il_out);
  gemm_bt<1><<<dim3(8,4,8), 256, 0, stream>>>(P, 1024, 1024ll*1024, VtOut, 1024, 512ll*1024, 1024,
                                              EpiPV{il_out, X, 1024});

  // GGNN G1: [nodes|h_in|h_out] @ [W_r|W_z] (k-rotated) -> rn into X[:,1536:2048), z
  gemm_bt<0><<<dim3(64,8,1), 256, 0, stream>>>(X, 2048, 0ll, Wrz_t, 1536, 0ll, 1536,
                                               EpiG1{cn_nodes, cn_br, cn_bz, X, zbuf});
  // GGNN G2: [h_in|h_out|rn] @ W_t -> gated output
  gemm_bt<0><<<dim3(64,4,1), 256, 0, stream>>>(X + 512, 2048, 0ll, Wt_t, 1536, 0ll, 1536,
                                               EpiG2{zbuf, cn_nodes, cn_bt, flags, (void*)d_out});
}

// Round 5
// 375.049 us; speedup vs baseline: 1.2769x; 1.0596x over previous
//
#include <hip/hip_runtime.h>
#include <hip/hip_bf16.h>
#include <stdint.h>

typedef unsigned short u16;
typedef __attribute__((ext_vector_type(8))) short bf16x8;
typedef __attribute__((ext_vector_type(4))) float floatx4;

__device__ __forceinline__ float bf2f(u16 v){ return __uint_as_float(((unsigned)v)<<16); }
__device__ __forceinline__ u16 f2bf(float f){
  unsigned u = __float_as_uint(f);
  unsigned r = 0x7fffu + ((u>>16)&1u);
  return (u16)((u+r)>>16);
}
__device__ __forceinline__ float lrelu(float x){ return x > 0.f ? x : 0.2f*x; }
__device__ __forceinline__ float sigm(float t){        // fast sigmoid, |err| ~1e-6
  t = fminf(fmaxf(t, -30.f), 30.f);
  return 1.f/(1.f + __expf(-t));
}

#define GLOAD16(ldsdst, gsrc) \
  __builtin_amdgcn_global_load_lds((const __attribute__((address_space(1))) void*)(gsrc), \
      (__attribute__((address_space(3))) void*)(ldsdst), 16, 0, 0)

// ---------------------------------------------------------------------------
// dtype detector: flags[0]=1 -> float inputs are f32; flags[1]=1 -> node_type int64
// ---------------------------------------------------------------------------
__global__ void k_detect(const u16* __restrict__ nodes_raw,
                         const int* __restrict__ ntype_raw, int* flags)
{
  __shared__ int s_wild, s_nz;
  if (threadIdx.x == 0){ s_wild = 0; s_nz = 0; }
  __syncthreads();
  int wild = 0;
#pragma unroll
  for (int i = 0; i < 16; i++){
    u16 w = nodes_raw[threadIdx.x*16 + i];
    int e = (w >> 7) & 0xFF;
    if (e != 0 && (e < 102 || e > 152)) wild++;
  }
  int nz = 0;
  if (threadIdx.x < 255 && ntype_raw[2*threadIdx.x + 1] != 0) nz = 1;
  atomicAdd(&s_wild, wild);
  atomicAdd(&s_nz, nz);
  __syncthreads();
  if (threadIdx.x == 0){
    flags[0] = (s_wild > 1024) ? 1 : 0;
    flags[1] = (s_nz == 0) ? 1 : 0;
  }
}

// --- merged canonicalization of all 13 float tensors (+ nodes into X) ------
struct CanonDesc {
  const void* src[13];
  u16*        dst[13];
  int startBlk[13];
  int n4[13];
};
__global__ __launch_bounds__(256)
void k_canon_all(CanonDesc d, u16* __restrict__ X, const int* __restrict__ flags)
{
  int blk = blockIdx.x;
  int seg = 0;
#pragma unroll
  for (int s = 1; s < 13; s++) if (blk >= d.startBlk[s]) seg = s;
  int i = (blk - d.startBlk[seg])*256 + threadIdx.x;
  if (i >= d.n4[seg]) return;
  uint2 bits;
  if (flags[0]) {
    float4 v = ((const float4*)d.src[seg])[i];
    ushort4 o2;
    o2.x = f2bf(v.x); o2.y = f2bf(v.y); o2.z = f2bf(v.z); o2.w = f2bf(v.w);
    bits = *(uint2*)&o2;
  } else {
    bits = ((const uint2*)d.src[seg])[i];
  }
  ((uint2*)d.dst[seg])[i] = bits;
  if (seg == 0) {               // nodes also -> X[:,0:512), ld 2048
    int e0 = i*4;
    long r = e0 >> 9;
    int  c = e0 & 511;
    *(uint2*)&X[r*2048 + c] = bits;
  }
}

// --- per-type row index lists ----------------------------------------------
__global__ void k_build_idx(const int* __restrict__ ntype, const int* __restrict__ flags,
                            int* __restrict__ idx, int* __restrict__ cnt)
{
  __shared__ int c[3];
  if (threadIdx.x < 3) c[threadIdx.x] = 0;
  __syncthreads();
  const int i64 = flags[1];
  for (int i = threadIdx.x; i < 8192; i += 256){
    int t = i64 ? ntype[2*i] : ntype[i];
    if (t >= 2 && t <= 4){
      int p = atomicAdd(&c[t-2], 1);
      idx[(t-2)*8192 + p] = i;
    }
  }
  __syncthreads();
  if (threadIdx.x < 3) cnt[threadIdx.x] = c[threadIdx.x];
}

// ---------------------------------------------------------------------------
// 128x128 bf16 GEMM, C = A(MxK) * B^T, 4-stage LDS ring, raw s_barrier +
// fine-grained vmcnt (never 0 mid-loop): 3 iterations of load lookahead.
// MODE 0: bm=bx, bn=by, bz=bzi.   MODE 1: bz=bx, bn=by, bm=bzi.
// ---------------------------------------------------------------------------
template<int MODE, class Epi>
__global__ __launch_bounds__(256)
void gemm_bt(const u16* __restrict__ A, int ldA, long sAz,
             const u16* __restrict__ B, int ldB, long sBz,
             int K, Epi epi)
{
  __shared__ __align__(16) u16 As[4][128][32];
  __shared__ __align__(16) u16 Bs[4][128][32];
  int bm, bn, bz;
  if (MODE == 0){ bm = blockIdx.x; bn = blockIdx.y; bz = blockIdx.z; }
  else          { bz = blockIdx.x; bn = blockIdx.y; bm = blockIdx.z; }
  const int tid  = threadIdx.x;
  const int lane = tid & 63;
  const int wave = tid >> 6;
  const int wm = (wave & 1) << 6;
  const int wn = (wave >> 1) << 6;
  const int mrow = lane & 15;
  const int quad = lane >> 4;

  const u16* Ab = A + (long)bz*sAz + (long)bm*128*ldA;
  const u16* Bb = B + (long)bz*sBz + (long)bn*128*ldB;
  const int srow = tid >> 2;
  const int scol = (tid & 3) << 3;
  const u16* gA0 = Ab + (long)srow*ldA + scol;
  const u16* gA1 = Ab + (long)(srow+64)*ldA + scol;
  const u16* gB0 = Bb + (long)srow*ldB + scol;
  const u16* gB1 = Bb + (long)(srow+64)*ldB + scol;

  floatx4 acc[4][4];
#pragma unroll
  for (int i=0;i<4;i++)
#pragma unroll
    for (int j=0;j<4;j++) acc[i][j] = 0.f;

  auto issue = [&](int buf){
    GLOAD16(&As[buf][srow][scol],    gA0);
    GLOAD16(&As[buf][srow+64][scol], gA1);
    GLOAD16(&Bs[buf][srow][scol],    gB0);
    GLOAD16(&Bs[buf][srow+64][scol], gB1);
    gA0 += 32; gA1 += 32; gB0 += 32; gB1 += 32;
  };

  issue(0); issue(1); issue(2);        // 3 stages in flight (12 loads/thread)
  const int nIter = K >> 5;
  for (int it = 0; it < nIter; ++it) {
    const int cur = it & 3;
    const int rem = nIter - 1 - it;
    // wait for stage `it` (oldest 4 loads); younger stages stay in flight
    if (rem >= 2)      asm volatile("s_waitcnt vmcnt(8)" ::: "memory");
    else if (rem == 1) asm volatile("s_waitcnt vmcnt(4)" ::: "memory");
    else               asm volatile("s_waitcnt vmcnt(0)" ::: "memory");
    asm volatile("s_barrier" ::: "memory");
    if (it + 3 < nIter) issue((it + 3) & 3);   // overwrites buf read at it-1
    bf16x8 af[4], bfr[4];
#pragma unroll
    for (int i=0;i<4;i++) af[i]  = *(const bf16x8*)&As[cur][wm + i*16 + mrow][quad*8];
#pragma unroll
    for (int i=0;i<4;i++) bfr[i] = *(const bf16x8*)&Bs[cur][wn + i*16 + mrow][quad*8];
#pragma unroll
    for (int mi=0;mi<4;mi++)
#pragma unroll
      for (int ni=0;ni<4;ni++)
        acc[mi][ni] = __builtin_amdgcn_mfma_f32_16x16x32_bf16(af[mi], bfr[ni], acc[mi][ni], 0,0,0);
  }

  // C/D layout: col = lane&15, row = quad*4 + reg  [m89/m91]
#pragma unroll
  for (int mi=0;mi<4;mi++)
#pragma unroll
    for (int ni=0;ni<4;ni++) {
      const int col  = (bn<<7) + wn + ni*16 + mrow;
      const int row0 = (bm<<7) + wm + mi*16 + quad*4;
#pragma unroll
      for (int r=0;r<4;r++)
        epi(row0 + r, col, bz, acc[mi][ni][r]);
    }
}

// ---------------------------------------------------------------------------
// Typed linear with row gather (same 4-stage pipeline; x=bm,y=bn,z=t)
// ---------------------------------------------------------------------------
__global__ __launch_bounds__(256)
void gemm_typed(const u16* __restrict__ A, const u16* __restrict__ B,
                const int* __restrict__ idx, const int* __restrict__ cnt,
                u16* __restrict__ node_in, u16* __restrict__ node_out)
{
  const int bz = blockIdx.z;
  const int count = cnt[bz];
  const int m0 = blockIdx.x << 7;
  if (m0 >= count) return;
  __shared__ __align__(16) u16 As[4][128][32];
  __shared__ __align__(16) u16 Bs[4][128][32];
  const int bn = blockIdx.y;
  const int tid  = threadIdx.x;
  const int lane = tid & 63;
  const int wave = tid >> 6;
  const int wm = (wave & 1) << 6;
  const int wn = (wave >> 1) << 6;
  const int mrow = lane & 15;
  const int quad = lane >> 4;
  const int* myidx = idx + bz*8192;

  const int srow = tid >> 2;
  const int scol = (tid & 3) << 3;
  int r0i = m0 + srow;      if (r0i >= count) r0i = m0;
  int r1i = m0 + srow + 64; if (r1i >= count) r1i = m0;
  const u16* gA0 = A + (long)myidx[r0i]*512 + scol;
  const u16* gA1 = A + (long)myidx[r1i]*512 + scol;
  const u16* Bb = B + (long)bz*1024*512 + (long)bn*128*512;
  const u16* gB0 = Bb + (long)srow*512 + scol;
  const u16* gB1 = Bb + (long)(srow+64)*512 + scol;

  floatx4 acc[4][4];
#pragma unroll
  for (int i=0;i<4;i++)
#pragma unroll
    for (int j=0;j<4;j++) acc[i][j] = 0.f;

  auto issue = [&](int buf){
    GLOAD16(&As[buf][srow][scol],    gA0);
    GLOAD16(&As[buf][srow+64][scol], gA1);
    GLOAD16(&Bs[buf][srow][scol],    gB0);
    GLOAD16(&Bs[buf][srow+64][scol], gB1);
    gA0 += 32; gA1 += 32; gB0 += 32; gB1 += 32;
  };

  issue(0); issue(1); issue(2);
  for (int it = 0; it < 16; ++it) {
    const int cur = it & 3;
    const int rem = 15 - it;
    if (rem >= 2)      asm volatile("s_waitcnt vmcnt(8)" ::: "memory");
    else if (rem == 1) asm volatile("s_waitcnt vmcnt(4)" ::: "memory");
    else               asm volatile("s_waitcnt vmcnt(0)" ::: "memory");
    asm volatile("s_barrier" ::: "memory");
    if (it + 3 < 16) issue((it + 3) & 3);
    bf16x8 af[4], bfr[4];
#pragma unroll
    for (int i=0;i<4;i++) af[i]  = *(const bf16x8*)&As[cur][wm + i*16 + mrow][quad*8];
#pragma unroll
    for (int i=0;i<4;i++) bfr[i] = *(const bf16x8*)&Bs[cur][wn + i*16 + mrow][quad*8];
#pragma unroll
    for (int mi=0;mi<4;mi++)
#pragma unroll
      for (int ni=0;ni<4;ni++)
        acc[mi][ni] = __builtin_amdgcn_mfma_f32_16x16x32_bf16(af[mi], bfr[ni], acc[mi][ni], 0,0,0);
  }

#pragma unroll
  for (int mi=0;mi<4;mi++) {
    const int lr0 = wm + mi*16 + quad*4;
#pragma unroll
    for (int r=0;r<4;r++) {
      const int lr = lr0 + r;
      if (m0 + lr >= count) continue;
      const long orig = myidx[m0 + lr];
#pragma unroll
      for (int ni=0;ni<4;ni++) {
        const int col = (bn<<7) + wn + ni*16 + mrow;
        u16 h = f2bf(acc[mi][ni][r]);
        if (col < 512) node_in [orig*512 + col]       = h;
        else           node_out[orig*512 + (col-512)] = h;
      }
    }
  }
}

// --- epilogues --------------------------------------------------------------
struct EpiPV {      // bz in [0,16): batch = bz&7, in/out = bz>>3
  const float* il; u16* X;
  __device__ void operator()(int row, int col, int bz, float v) const {
    long gr = (long)(bz & 7)*1024 + row;
    int colOff = 512 + ((bz >> 3) << 9);
    X[gr*2048 + colOff + col] = f2bf(v * il[(long)(bz>>3)*8192 + gr]);
  }
};
struct EpiG1 {      // col<512: rn -> X[:,1536+col]; else z -> zbuf (bf16)
  const u16* nodes; const u16* b_r; const u16* b_z; u16* X; u16* zbuf;
  __device__ void operator()(int row, int col, int bz, float v) const {
    if (col < 512) {
      float r = sigm(v + bf2f(b_r[col]));
      X[(long)row*2048 + 1536 + col] = f2bf(r * bf2f(nodes[(long)row*512 + col]));
    } else {
      int c = col - 512;
      zbuf[(long)row*512 + c] = f2bf(sigm(v + bf2f(b_z[c])));
    }
  }
};
struct EpiG2 {      // h_hat = tanh(v + b_t) = 2*sigm(2t)-1; out = (1-z)n + z h_hat
  const u16* zbuf; const u16* nodes; const u16* b_t; const int* flags; void* out;
  __device__ void operator()(int row, int col, int bz, float v) const {
    long idx = (long)row*512 + col;
    float t = fminf(fmaxf(v + bf2f(b_t[col]), -15.f), 15.f);
    float h = 2.f*sigm(2.f*t) - 1.f;
    float z = bf2f(zbuf[idx]);
    float nv = bf2f(nodes[idx]);
    float o2 = (1.f - z)*nv + z*h;
    if (flags[0]) ((float*)out)[idx] = o2;
    else          ((u16*)out)[idx]   = f2bf(o2);
  }
};

// --- merged weight transposes: 9 slices ------------------------------------
struct TrDesc {
  const u16* src[9]; u16* dst[9]; int rot[9]; int ldD[9]; int rows[9]; int modK[9];
};
__global__ __launch_bounds__(256)
void k_wtrans(TrDesc d)
{
  __shared__ u16 tile[32][33];
  const int z = blockIdx.z;
  const int r0 = blockIdx.y*32;
  if (r0 >= d.rows[z]) return;
  const u16* src = d.src[z];
  u16* dst = d.dst[z];
  const int c0 = blockIdx.x*32;
  const int tx = threadIdx.x, ty = threadIdx.y;
#pragma unroll
  for (int i=0;i<32;i+=8)
    tile[ty+i][tx] = src[(long)(r0+ty+i)*512 + c0 + tx];
  __syncthreads();
  const int k0 = (r0 + d.rot[z]) % d.modK[z];
#pragma unroll
  for (int i=0;i<32;i+=8)
    dst[(long)(c0+ty+i)*d.ldD[z] + k0 + tx] = tile[tx][ty+i];
}

// --- merged V transposes ---------------------------------------------------
__global__ __launch_bounds__(256)
void k_vtrans(const u16* __restrict__ nin, const u16* __restrict__ nout,
              u16* __restrict__ vin, u16* __restrict__ vout)
{
  __shared__ u16 tile[32][33];
  const int z = blockIdx.z;
  const int b = z & 7;
  const u16* src = (z < 8 ? nin : nout) + (long)b*1024*512;
  u16* dst = (z < 8 ? vin : vout) + (long)b*512*1024;
  const int c0 = blockIdx.x*32, r0 = blockIdx.y*32;
  const int tx = threadIdx.x, ty = threadIdx.y;
#pragma unroll
  for (int i=0;i<32;i+=8)
    tile[ty+i][tx] = src[(long)(r0+ty+i)*512 + c0 + tx];
  __syncthreads();
#pragma unroll
  for (int i=0;i<32;i+=8)
    dst[(long)(c0+ty+i)*1024 + r0 + tx] = tile[tx][ty+i];
}

__device__ __forceinline__ void load8f(float* f, const u16* p){
  uint4 q = *(const uint4*)p;
  unsigned w[4] = {q.x, q.y, q.z, q.w};
#pragma unroll
  for (int i=0;i<4;i++){ f[2*i] = bf2f((u16)(w[i]&0xffffu)); f[2*i+1] = bf2f((u16)(w[i]>>16)); }
}

// --- per-row scalar projections --------------------------------------------
__global__ __launch_bounds__(256)
void k_svec(const u16* __restrict__ nodes, const u16* __restrict__ nin, const u16* __restrict__ nout,
            const u16* __restrict__ aiq, const u16* __restrict__ aiv,
            const u16* __restrict__ aoq, const u16* __restrict__ aov,
            float* sq_all, float* sv_all)
{
  const int lane = threadIdx.x & 63, wave = threadIdx.x >> 6;
  const long row = (long)blockIdx.x*4 + wave;
  const int c = lane << 3;
  float xn[8], xi[8], xo[8], q1[8], v1[8], q2[8], v2[8];
  load8f(xn, nodes + row*512 + c);
  load8f(xi, nin   + row*512 + c);
  load8f(xo, nout  + row*512 + c);
  load8f(q1, aiq + c); load8f(v1, aiv + c);
  load8f(q2, aoq + c); load8f(v2, aov + c);
  float s0=0,s1=0,s2=0,s3=0;
#pragma unroll
  for (int j=0;j<8;j++){ s0 += xn[j]*q1[j]; s1 += xn[j]*q2[j]; s2 += xi[j]*v1[j]; s3 += xo[j]*v2[j]; }
#pragma unroll
  for (int off=32; off; off>>=1){
    s0 += __shfl_xor(s0, off);
    s1 += __shfl_xor(s1, off);
    s2 += __shfl_xor(s2, off);
    s3 += __shfl_xor(s3, off);
  }
  if (lane==0){
    sq_all[row] = s0; sq_all[8192 + row] = s1;
    sv_all[row] = s2; sv_all[8192 + row] = s3;
  }
}

// --- masked-softmax stats + materialize P (bf16); y selects in/out ---------
__global__ __launch_bounds__(256)
void k_stats(const int* __restrict__ mask, const float* __restrict__ sq_all,
             const float* __restrict__ sv_all, u16* __restrict__ P, float* __restrict__ il_all)
{
  const int lane = threadIdx.x & 63, wave = threadIdx.x >> 6;
  const long row = (long)blockIdx.x*4 + wave;           // within 8192
  const long gr  = (long)blockIdx.y*8192 + row;         // global (in/out)
  const int* mrow = mask + gr*1024;
  const float* svb = sv_all + (long)blockIdx.y*8192 + (row >> 10)*1024;
  const float qs = sq_all[gr];
  float m = -3.0e38f;
  float e[4][4];
#pragma unroll
  for (int it=0; it<4; ++it) {
    int j = it*256 + lane*4;
    int4 mk = *(const int4*)&mrow[j];
    float4 s = *(const float4*)&svb[j];
    e[it][0] = mk.x > 0 ? lrelu(qs + s.x) : -1e9f;
    e[it][1] = mk.y > 0 ? lrelu(qs + s.y) : -1e9f;
    e[it][2] = mk.z > 0 ? lrelu(qs + s.z) : -1e9f;
    e[it][3] = mk.w > 0 ? lrelu(qs + s.w) : -1e9f;
    m = fmaxf(m, fmaxf(fmaxf(e[it][0], e[it][1]), fmaxf(e[it][2], e[it][3])));
  }
#pragma unroll
  for (int off=32; off; off>>=1) m = fmaxf(m, __shfl_xor(m, off));
  float l = 0.f;
#pragma unroll
  for (int it=0; it<4; ++it) {
    int j = it*256 + lane*4;
    float p0 = __expf(e[it][0] - m), p1 = __expf(e[it][1] - m);
    float p2 = __expf(e[it][2] - m), p3 = __expf(e[it][3] - m);
    ushort4 pk;
    pk.x = f2bf(p0); pk.y = f2bf(p1); pk.z = f2bf(p2); pk.w = f2bf(p3);
    *(ushort4*)&P[gr*1024 + j] = pk;
    l += (p0 + p1) + (p2 + p3);
  }
#pragma unroll
  for (int off=32; off; off>>=1) l += __shfl_xor(l, off);
  if (lane==0) il_all[gr] = 1.f / l;
}

// ---------------------------------------------------------------------------
extern "C" void kernel_launch(void* const* d_in, const int* in_sizes, int n_in,
                              void* d_out, int out_size, void* d_ws, size_t ws_size,
                              hipStream_t stream)
{
  const void* nodes_r = d_in[0];
  const int*  mask    = (const int*)d_in[1];
  const int*  ntype   = (const int*)d_in[2];

  char* base = (char*)d_ws;
  size_t o = 0;
  auto alloc = [&](size_t bytes){ void* p = base + o; o += (bytes + 255) & ~size_t(255); return p; };
  int*  flags   = (int*)alloc(256);
  int*  cnt     = (int*)alloc(256);
  int*  idx     = (int*)alloc(3ll*8192*4);
  u16* cn_nodes = (u16*)alloc(8192ll*512*2);
  u16* cn_Win   = (u16*)alloc(3ll*512*512*2);
  u16* cn_Wout  = (u16*)alloc(3ll*512*512*2);
  u16* cn_Wr    = (u16*)alloc(1536ll*512*2);
  u16* cn_Wz    = (u16*)alloc(1536ll*512*2);
  u16* cn_Wt    = (u16*)alloc(1536ll*512*2);
  u16* cn_aiq   = (u16*)alloc(512*2);
  u16* cn_aiv   = (u16*)alloc(512*2);
  u16* cn_aoq   = (u16*)alloc(512*2);
  u16* cn_aov   = (u16*)alloc(512*2);
  u16* cn_br    = (u16*)alloc(512*2);
  u16* cn_bz    = (u16*)alloc(512*2);
  u16* cn_bt    = (u16*)alloc(512*2);
  u16* node_in  = (u16*)alloc(8192ll*512*2);   // zbuf aliases this after svec
  u16* node_out = (u16*)alloc(8192ll*512*2);   // adjacent (joint memset)
  u16* Vt       = (u16*)alloc(16ll*512*1024*2); // [in 8 | out 8] batches
  u16* X        = (u16*)alloc(8192ll*2048*2);   // [nodes|h_in|h_out|rn], ld 2048
  u16* P        = (u16*)alloc(16ll*1024*1024*2);// [in 8 | out 8] batches
  u16* Wio_t    = (u16*)alloc(3ll*1024*512*2);
  u16* Wrz_t    = (u16*)alloc(1024ll*1536*2);
  u16* Wt_t     = (u16*)alloc(512ll*1536*2);
  float* sq_all = (float*)alloc(16384*4);
  float* sv_all = (float*)alloc(16384*4);
  float* il_all = (float*)alloc(16384*4);
  u16* zbuf = node_in;   // alias: node_in last read by k_svec; zbuf written at G1

  hipMemsetAsync(node_in, 0, 2ll*8192*512*2, stream);   // node_in + node_out

  k_detect<<<1, 256, 0, stream>>>((const u16*)nodes_r, ntype, flags);

  // merged canon of 13 tensors (+ nodes into X)
  CanonDesc cd;
  const int canonN[13] = {8192*512, 3*512*512, 3*512*512, 1536*512, 1536*512, 1536*512,
                          512,512,512,512,512,512,512};
  u16* canonDst[13] = {cn_nodes, cn_Win, cn_Wout, cn_Wr, cn_Wz, cn_Wt,
                       cn_aiq, cn_aiv, cn_aoq, cn_aov, cn_br, cn_bz, cn_bt};
  const int canonSrcIdx[13] = {0,3,4,9,11,13,5,6,7,8,10,12,14};
  int blk = 0;
  for (int s=0;s<13;s++){
    cd.src[s] = d_in[canonSrcIdx[s]];
    cd.dst[s] = canonDst[s];
    cd.n4[s]  = canonN[s]/4;
    cd.startBlk[s] = blk;
    blk += (cd.n4[s] + 255)/256;
  }
  k_canon_all<<<blk, 256, 0, stream>>>(cd, X, flags);

  k_build_idx<<<1, 256, 0, stream>>>(ntype, flags, idx, cnt);

  // merged weight transposes
  TrDesc td;
  td.src[0]=cn_Wr; td.src[1]=cn_Wz; td.src[2]=cn_Wt;
  td.dst[0]=Wrz_t; td.dst[1]=Wrz_t + 512ll*1536; td.dst[2]=Wt_t;
  td.rot[0]=512; td.rot[1]=512; td.rot[2]=0;
  td.ldD[0]=1536; td.ldD[1]=1536; td.ldD[2]=1536;
  td.rows[0]=1536; td.rows[1]=1536; td.rows[2]=1536;
  td.modK[0]=1536; td.modK[1]=1536; td.modK[2]=1536;
  for (int t=0;t<3;t++){
    td.src[3+t]=cn_Win  + (long)t*512*512; td.dst[3+t]=Wio_t + (long)t*1024*512;
    td.src[6+t]=cn_Wout + (long)t*512*512; td.dst[6+t]=Wio_t + (long)t*1024*512 + 512ll*512;
    td.rot[3+t]=td.rot[6+t]=0; td.ldD[3+t]=td.ldD[6+t]=512;
    td.rows[3+t]=td.rows[6+t]=512; td.modK[3+t]=td.modK[6+t]=512;
  }
  k_wtrans<<<dim3(16,48,9), dim3(32,8), 0, stream>>>(td);

  // typed linear, gathered rows
  gemm_typed<<<dim3(64,8,3), 256, 0, stream>>>(cn_nodes, Wio_t, idx, cnt, node_in, node_out);

  // V^T for PV B-operands
  k_vtrans<<<dim3(16,32,16), dim3(32,8), 0, stream>>>(node_in, node_out, Vt, Vt + 8ll*512*1024);

  k_svec<<<2048, 256, 0, stream>>>(cn_nodes, node_in, node_out, cn_aiq, cn_aiv, cn_aoq, cn_aov,
                                   sq_all, sv_all);

  // merged stats (in + out)
  k_stats<<<dim3(2048,2), 256, 0, stream>>>(mask, sq_all, sv_all, P, il_all);

  // merged PV GEMMs: bz 0..15 (batch | in/out), writes X[:,512:1536)
  gemm_bt<1><<<dim3(16,4,8), 256, 0, stream>>>(P, 1024, 1024ll*1024, Vt, 1024, 512ll*1024, 1024,
                                               EpiPV{il_all, X});

  // GGNN G1: [nodes|h_in|h_out] @ [W_r|W_z] (k-rotated) -> rn into X[:,1536:2048), z
  gemm_bt<0><<<dim3(64,8,1), 256, 0, stream>>>(X, 2048, 0ll, Wrz_t, 1536, 0ll, 1536,
                                               EpiG1{cn_nodes, cn_br, cn_bz, X, zbuf});
  // GGNN G2: [h_in|h_out|rn] @ W_t -> gated output
  gemm_bt<0><<<dim3(64,4,1), 256, 0, stream>>>(X + 512, 2048, 0ll, Wt_t, 1536, 0ll, 1536,
                                               EpiG2{zbuf, cn_nodes, cn_bt, flags, (void*)d_out});
}